// Round 1
// baseline (3295.531 us; speedup 1.0000x reference)
//
#include <hip/hip_runtime.h>

// Problem constants
#define NR   300
#define NB   4
#define NN   512
#define TT   2048          // NB*NN
#define CH   30            // regions per chunk
#define NCH  10            // chunks
#define SLC  8             // k-slice blocks per region (64 k each)

#define TAU   0.8f
#define OMT   0.2f         // 1-TAU
#define ALPH  0.05f
#define OMA   0.95f
#define LRQ   5.0e-6f      // HEBB_LR / B = 2e-5/4
#define NSC   0.02f

// ---------------- v_init = v_s0 + 0.02*noise ----------------
__global__ __launch_bounds__(256) void k_init(const float* __restrict__ vs0,
                                              const float* __restrict__ noise,
                                              float* __restrict__ v_init) {
    int idx = blockIdx.x * 256 + threadIdx.x;           // float4 index, 600*256 = 153600
    const float4* a = (const float4*)vs0;
    const float4* b = (const float4*)noise;
    float4* o = (float4*)v_init;
    float4 va = a[idx], vb = b[idx];
    float4 r;
    r.x = va.x + NSC * vb.x; r.y = va.y + NSC * vb.y;
    r.z = va.z + NSC * vb.z; r.w = va.w + NSC * vb.w;
    o[idx] = r;
}

// ---------------- X[i,t] = inp[i,t] + sum_j A[j,i]*v_init[j,t] ----------------
// grid = 20 region-groups (15 regions each) x 8 t-chunks = 160 blocks
__global__ __launch_bounds__(256) void k_base(const float* __restrict__ A,
                                              const float* __restrict__ v_init,
                                              const float* __restrict__ inp,
                                              float* __restrict__ X) {
    const int gid = blockIdx.x >> 3;       // region group
    const int tch = blockIdx.x & 7;
    const int i0  = gid * 15;
    const int t   = tch * 256 + threadIdx.x;

    __shared__ float As[NR * 15];
    for (int idx = threadIdx.x; idx < NR * 15; idx += 256) {
        int j = idx / 15, g = idx % 15;
        As[idx] = A[j * NR + i0 + g];
    }
    __syncthreads();

    float acc[15];
#pragma unroll
    for (int g = 0; g < 15; g++) acc[g] = 0.f;

    for (int j = 0; j < NR; j++) {
        float v = v_init[(size_t)j * TT + t];
#pragma unroll
        for (int g = 0; g < 15; g++) acc[g] += As[j * 15 + g] * v;
    }
#pragma unroll
    for (int g = 0; g < 15; g++)
        X[(size_t)(i0 + g) * TT + t] = inp[(size_t)(i0 + g) * TT + t] + acc[g];
}

// ---------------- cross-chunk delta fold: X[i] += sum_{j<c0} A[j,i]*delta[j] ----------------
__global__ __launch_bounds__(256) void k_pre(const float* __restrict__ A,
                                             const float* __restrict__ delta,
                                             float* __restrict__ X, int c0) {
    const int rb = blockIdx.x >> 3;
    const int tch = blockIdx.x & 7;
    const int i = c0 + rb;
    const int t = tch * 256 + threadIdx.x;
    float acc = X[(size_t)i * TT + t];
    for (int j = 0; j < c0; j++)
        acc += A[(size_t)j * NR + i] * delta[(size_t)j * TT + t];
    X[(size_t)i * TT + t] = acc;
}

// ---------------- sequential chain for one chunk (+fused Hebbian W update) ----------------
// grid = CH*SLC = 240 blocks (all resident; spin-safe). block = (region-in-chunk, k-slice)
__global__ __launch_bounds__(256, 1) void k_chain(
    const float* __restrict__ W,   const float* __restrict__ vb0,
    const float* __restrict__ va0, const float* __restrict__ A,
    const float* __restrict__ v_init, const float* __restrict__ X,
    const float* __restrict__ rbar0,  const float* __restrict__ ebar0,
    float* __restrict__ delta, int* __restrict__ cnt,
    float* __restrict__ out_sp, float* __restrict__ outW,
    double* __restrict__ fpart, int c0) {

    const int tid = threadIdx.x;
    const int rb  = blockIdx.x >> 3;
    const int q   = blockIdx.x & 7;
    const int i   = c0 + rb;
    const int k_local = tid >> 2;        // 0..63
    const int mq  = tid & 3;             // m-quarter AND b-lane
    const int kg  = q * 64 + k_local;    // global output column

    __shared__ __align__(16) float xs[TT];
    __shared__ double ps[4];

    // --- preload W slice into registers: w[s] = W[i][mq*128+s][kg] (off critical path) ---
    float w[128];
    const float* Wp = W + (((size_t)i * NN + (size_t)mq * 128) * NN) + kg;
#pragma unroll
    for (int s = 0; s < 128; s++) w[s] = Wp[(size_t)s * NN];

    // --- x init from X (inp + base + cross-chunk deltas) ---
#pragma unroll
    for (int s = 0; s < 8; s++) { int t = tid + s * 256; xs[t] = X[(size_t)i * TT + t]; }

    // --- within-chunk gather: wait for each predecessor, accumulate its delta ---
    for (int j = c0; j < i; j++) {
        if (tid == 0) {
            while (__hip_atomic_load(&cnt[j], __ATOMIC_ACQUIRE, __HIP_MEMORY_SCOPE_AGENT) < SLC)
                __builtin_amdgcn_s_sleep(1);
        }
        __syncthreads();
        float a = A[(size_t)j * NR + i];
        const float* dp = delta + (size_t)j * TT;
#pragma unroll
        for (int s = 0; s < 8; s++) { int t = tid + s * 256; xs[t] += a * dp[t]; }
    }
    __syncthreads();

    // --- GEMM: pred[b][kg] = sum_m x[b][m] * W[m][kg], m-quarter per lane, quad-reduced ---
    float acc0 = 0.f, acc1 = 0.f, acc2 = 0.f, acc3 = 0.f;
#pragma unroll
    for (int s4 = 0; s4 < 32; s4++) {
        const int mb = mq * 128 + s4 * 4;
        float4 x0 = *(const float4*)&xs[mb];
        float4 x1 = *(const float4*)&xs[NN + mb];
        float4 x2 = *(const float4*)&xs[2 * NN + mb];
        float4 x3 = *(const float4*)&xs[3 * NN + mb];
        const float w0 = w[s4 * 4], w1 = w[s4 * 4 + 1], w2 = w[s4 * 4 + 2], w3 = w[s4 * 4 + 3];
        acc0 += x0.x * w0 + x0.y * w1 + x0.z * w2 + x0.w * w3;
        acc1 += x1.x * w0 + x1.y * w1 + x1.z * w2 + x1.w * w3;
        acc2 += x2.x * w0 + x2.y * w1 + x2.z * w2 + x2.w * w3;
        acc3 += x3.x * w0 + x3.y * w1 + x3.z * w2 + x3.w * w3;
    }
    acc0 += __shfl_xor(acc0, 1); acc0 += __shfl_xor(acc0, 2);
    acc1 += __shfl_xor(acc1, 1); acc1 += __shfl_xor(acc1, 2);
    acc2 += __shfl_xor(acc2, 1); acc2 += __shfl_xor(acc2, 2);
    acc3 += __shfl_xor(acc3, 1); acc3 += __shfl_xor(acc3, 2);
    const float pred = (mq == 0) ? acc0 : (mq == 1) ? acc1 : (mq == 2) ? acc2 : acc3;

    // --- elementwise state update for (b=mq, n=kg) ---
    const size_t base = (size_t)i * TT + (size_t)mq * NN + kg;
    const float vb  = TAU * vb0[base] + OMT * pred;
    const float va  = TAU * va0[base];
    const float vsi = v_init[base];
    const float vs  = TAU * vsi + OMT * (vb - va);
    out_sp[base] = (vs > 0.f) ? 1.f : 0.f;
    delta[base]  = vs - vsi;
    const float mis = vs - vb;

    // --- publish delta (release flag ASAP; Hebbian work happens after, overlapped) ---
    __syncthreads();   // all lanes' delta stores drained (vmcnt) before release
    if (tid == 0)
        __hip_atomic_fetch_add(&cnt[i], 1, __ATOMIC_RELEASE, __HIP_MEMORY_SCOPE_AGENT);

    // --- fused Hebbian update: rbar in-place into xs, ebar via quad shuffle ---
#pragma unroll
    for (int s = 0; s < 8; s++) {
        int t = tid + s * 256;
        xs[t] = OMA * rbar0[(size_t)i * TT + t] + ALPH * xs[t];
    }
    __syncthreads();

    const float e_own = OMA * ebar0[base] + ALPH * mis;
    const int lane = tid & 63, qb = lane & ~3;
    const float e0 = __shfl(e_own, qb + 0);
    const float e1 = __shfl(e_own, qb + 1);
    const float e2 = __shfl(e_own, qb + 2);
    const float e3 = __shfl(e_own, qb + 3);

#pragma unroll
    for (int s = 0; s < 128; s++) {
        const int m = mq * 128 + s;
        const float dw = e0 * xs[m] + e1 * xs[NN + m] + e2 * xs[2 * NN + m] + e3 * xs[3 * NN + m];
        outW[(((size_t)i * NN + m) * NN) + kg] = w[s] + LRQ * dw;
    }

    // --- F partial (deterministic per-block double) ---
    double p = (double)mis * (double)mis;
#pragma unroll
    for (int off = 32; off; off >>= 1) p += __shfl_xor(p, off);
    if (lane == 0) ps[tid >> 6] = p;
    __syncthreads();
    if (tid == 0) fpart[(size_t)(c0 / CH) * (CH * SLC) + blockIdx.x] = ps[0] + ps[1] + ps[2] + ps[3];
}

// ---------------- final F reduction ----------------
__global__ __launch_bounds__(256) void k_fin(const double* __restrict__ fpart,
                                             float* __restrict__ outF) {
    __shared__ double ps[256];
    double s = 0.0;
    for (int idx = threadIdx.x; idx < NCH * CH * SLC; idx += 256) s += fpart[idx];
    ps[threadIdx.x] = s;
    __syncthreads();
    for (int st = 128; st; st >>= 1) {
        if (threadIdx.x < st) ps[threadIdx.x] += ps[threadIdx.x + st];
        __syncthreads();
    }
    if (threadIdx.x == 0) outF[0] = (float)(ps[0] / 614400.0);
}

extern "C" void kernel_launch(void* const* d_in, const int* in_sizes, int n_in,
                              void* d_out, int out_size, void* d_ws, size_t ws_size,
                              hipStream_t stream) {
    const float* v_s0  = (const float*)d_in[0];
    const float* v_b0  = (const float*)d_in[1];
    const float* v_a0  = (const float*)d_in[2];
    const float* rbar0 = (const float*)d_in[3];
    const float* ebar0 = (const float*)d_in[4];
    const float* W     = (const float*)d_in[5];
    const float* A     = (const float*)d_in[6];
    const float* inp   = (const float*)d_in[7];
    const float* noise = (const float*)d_in[8];

    float* out_sp = (float*)d_out;                 // [300,4,512]
    float* out_W  = out_sp + 614400;               // [300,512,512]
    float* out_F  = out_sp + 79257600;             // scalar

    char* ws = (char*)d_ws;
    float* v_init = (float*)ws;                        // 614400 f
    float* X      = v_init + 614400;                   // 614400 f
    float* delta  = X + 614400;                        // 614400 f
    int*   cnt    = (int*)(ws + 3ull * 2457600);       // 300 ints
    double* fpart = (double*)(ws + 7374000);           // 2400 doubles

    hipMemsetAsync(cnt, 0, NR * sizeof(int), stream);
    k_init<<<600, 256, 0, stream>>>(v_s0, noise, v_init);
    k_base<<<160, 256, 0, stream>>>(A, v_init, inp, X);
    for (int c = 0; c < NCH; c++) {
        int c0 = c * CH;
        if (c) k_pre<<<CH * SLC, 256, 0, stream>>>(A, delta, X, c0);
        k_chain<<<CH * SLC, 256, 0, stream>>>(W, v_b0, v_a0, A, v_init, X,
                                              rbar0, ebar0, delta, cnt,
                                              out_sp, out_W, fpart, c0);
    }
    k_fin<<<1, 256, 0, stream>>>(fpart, out_F);
}

// Round 2
// 2321.339 us; speedup vs baseline: 1.4197x; 1.4197x over previous
//
#include <hip/hip_runtime.h>

// Problem constants
#define NR   300
#define NB   4
#define NN   512
#define TT   2048          // NB*NN
#define CH   30            // regions per chunk
#define NCH  10            // chunks
#define SLC  8             // k-slice blocks per region (64 k each)

#define TAU   0.8f
#define OMT   0.2f         // 1-TAU
#define ALPH  0.05f
#define OMA   0.95f
#define LRQ   5.0e-6f      // HEBB_LR / B = 2e-5/4
#define NSC   0.02f

// padded LDS x layout: [b][quarter][128] with quarter stride 136 floats
// (136 % 32 == 8 -> quarters land on bank offsets 0/8/16/24: conflict-free)
#define QSTR 136
#define BSTR 544           // 4*136
__device__ __forceinline__ int xidx(int b, int n) {
    return b * BSTR + (n >> 7) * QSTR + (n & 127);
}

// ---------------- v_init = v_s0 + 0.02*noise ----------------
__global__ __launch_bounds__(256) void k_init(const float* __restrict__ vs0,
                                              const float* __restrict__ noise,
                                              float* __restrict__ v_init) {
    int idx = blockIdx.x * 256 + threadIdx.x;           // float4 index, 600*256 = 153600
    const float4* a = (const float4*)vs0;
    const float4* b = (const float4*)noise;
    float4* o = (float4*)v_init;
    float4 va = a[idx], vb = b[idx];
    float4 r;
    r.x = va.x + NSC * vb.x; r.y = va.y + NSC * vb.y;
    r.z = va.z + NSC * vb.z; r.w = va.w + NSC * vb.w;
    o[idx] = r;
}

// ---------------- X[i,t] = inp[i,t] + sum_j A[j,i]*v_init[j,t] ----------------
__global__ __launch_bounds__(256) void k_base(const float* __restrict__ A,
                                              const float* __restrict__ v_init,
                                              const float* __restrict__ inp,
                                              float* __restrict__ X) {
    const int gid = blockIdx.x >> 3;       // region group (15 regions)
    const int tch = blockIdx.x & 7;
    const int i0  = gid * 15;
    const int t   = tch * 256 + threadIdx.x;

    __shared__ float As[NR * 15];
    for (int idx = threadIdx.x; idx < NR * 15; idx += 256) {
        int j = idx / 15, g = idx % 15;
        As[idx] = A[j * NR + i0 + g];
    }
    __syncthreads();

    float acc[15];
#pragma unroll
    for (int g = 0; g < 15; g++) acc[g] = 0.f;

    for (int j = 0; j < NR; j++) {
        float v = v_init[(size_t)j * TT + t];
#pragma unroll
        for (int g = 0; g < 15; g++) acc[g] += As[j * 15 + g] * v;
    }
#pragma unroll
    for (int g = 0; g < 15; g++)
        X[(size_t)(i0 + g) * TT + t] = inp[(size_t)(i0 + g) * TT + t] + acc[g];
}

// ---------------- cross-chunk delta fold: X[i] += sum_{j<c0} A[j,i]*delta[j] ----------------
__global__ __launch_bounds__(256) void k_pre(const float* __restrict__ A,
                                             const float* __restrict__ delta,
                                             float* __restrict__ X, int c0) {
    const int rb = blockIdx.x >> 3;
    const int tch = blockIdx.x & 7;
    const int i = c0 + rb;
    const int t = tch * 256 + threadIdx.x;
    float acc = X[(size_t)i * TT + t];
    for (int j = 0; j < c0; j++)
        acc += A[(size_t)j * NR + i] * delta[(size_t)j * TT + t];
    X[(size_t)i * TT + t] = acc;
}

// ---------------- sequential chain for one chunk (+fused Hebbian W update) ----------------
// grid = CH*SLC = 240 blocks (all resident; spin-safe).
// Sync protocol: delta + cnt use RELAXED agent-scope atomics (sc0/sc1 -> IC-coherent,
// NO buffer_inv / buffer_wbl2 on the critical path). Ordering: explicit vmcnt(0)
// before the flag-releasing barrier; reader's branch on polled value orders sc1 loads.
__global__ __launch_bounds__(256, 1) void k_chain(
    const float* __restrict__ W,   const float* __restrict__ vb0,
    const float* __restrict__ va0, const float* __restrict__ A,
    const float* __restrict__ v_init, const float* __restrict__ X,
    const float* __restrict__ rbar0,  const float* __restrict__ ebar0,
    float* __restrict__ delta, int* __restrict__ cnt,
    float* __restrict__ out_sp, float* __restrict__ outW,
    double* __restrict__ fpart, int c0) {

    const int tid = threadIdx.x;
    const int rb  = blockIdx.x >> 3;
    const int q   = blockIdx.x & 7;
    const int i   = c0 + rb;
    const int k_local = tid >> 2;        // 0..63
    const int mq  = tid & 3;             // m-quarter AND b-lane
    const int kg  = q * 64 + k_local;    // global output column

    __shared__ __align__(16) float xs[4 * BSTR];
    __shared__ float As[CH];
    __shared__ double ps[4];

    // --- preload per-thread state scalars (off critical path) ---
    const size_t base = (size_t)i * TT + (size_t)mq * NN + kg;
    const float vb0v = vb0[base];
    const float va0v = va0[base];
    const float vsi  = v_init[base];
    const float eb0v = ebar0[base];

    if (tid < CH) As[tid] = A[(size_t)(c0 + tid) * NR + i];

    // --- preload W slice into registers: w[s] = W[i][mq*128+s][kg] ---
    float w[128];
    const float* Wp = W + (((size_t)i * NN + (size_t)mq * 128) * NN) + kg;
#pragma unroll
    for (int s = 0; s < 128; s++) w[s] = Wp[(size_t)s * NN];

    // --- x init from X (inp + base + cross-chunk deltas) ---
#pragma unroll
    for (int s = 0; s < 8; s++) {
        int t = tid + s * 256;
        xs[xidx(t >> 9, t & 511)] = X[(size_t)i * TT + t];
    }

    // --- within-chunk gather: wait for each predecessor, accumulate its delta ---
    for (int j = c0; j < i; j++) {
        if (tid == 0) {
            while (__hip_atomic_load(&cnt[j], __ATOMIC_RELAXED, __HIP_MEMORY_SCOPE_AGENT) < SLC)
                __builtin_amdgcn_s_sleep(1);
        }
        __syncthreads();
        asm volatile("" ::: "memory");
        const float a = As[j - c0];
        const float* dp = delta + (size_t)j * TT;
#pragma unroll
        for (int s = 0; s < 8; s++) {
            int t = tid + s * 256;
            float dv = __hip_atomic_load(&dp[t], __ATOMIC_RELAXED, __HIP_MEMORY_SCOPE_AGENT);
            xs[xidx(t >> 9, t & 511)] += a * dv;
        }
    }
    __syncthreads();

    // --- GEMM: pred[b][kg] = sum_m x[b][m]*W[m][kg]; per-lane order identical to R1 ---
    float acc0 = 0.f, acc1 = 0.f, acc2 = 0.f, acc3 = 0.f;
#pragma unroll
    for (int s4 = 0; s4 < 32; s4++) {
        const int mb = mq * QSTR + s4 * 4;
        float4 x0 = *(const float4*)&xs[mb];
        float4 x1 = *(const float4*)&xs[BSTR + mb];
        float4 x2 = *(const float4*)&xs[2 * BSTR + mb];
        float4 x3 = *(const float4*)&xs[3 * BSTR + mb];
        const float w0 = w[s4 * 4], w1 = w[s4 * 4 + 1], w2 = w[s4 * 4 + 2], w3 = w[s4 * 4 + 3];
        acc0 += x0.x * w0 + x0.y * w1 + x0.z * w2 + x0.w * w3;
        acc1 += x1.x * w0 + x1.y * w1 + x1.z * w2 + x1.w * w3;
        acc2 += x2.x * w0 + x2.y * w1 + x2.z * w2 + x2.w * w3;
        acc3 += x3.x * w0 + x3.y * w1 + x3.z * w2 + x3.w * w3;
    }
    acc0 += __shfl_xor(acc0, 1); acc0 += __shfl_xor(acc0, 2);
    acc1 += __shfl_xor(acc1, 1); acc1 += __shfl_xor(acc1, 2);
    acc2 += __shfl_xor(acc2, 1); acc2 += __shfl_xor(acc2, 2);
    acc3 += __shfl_xor(acc3, 1); acc3 += __shfl_xor(acc3, 2);
    const float pred = (mq == 0) ? acc0 : (mq == 1) ? acc1 : (mq == 2) ? acc2 : acc3;

    // --- elementwise state update for (b=mq, n=kg) ---
    const float vb  = TAU * vb0v + OMT * pred;
    const float va  = TAU * va0v;
    const float vs  = TAU * vsi + OMT * (vb - va);
    out_sp[base] = (vs > 0.f) ? 1.f : 0.f;
    __hip_atomic_store(&delta[base], vs - vsi, __ATOMIC_RELAXED, __HIP_MEMORY_SCOPE_AGENT);
    const float mis = vs - vb;

    // --- publish: every wave drains its stores to the coherence point, then flag ---
    asm volatile("s_waitcnt vmcnt(0)" ::: "memory");
    __syncthreads();
    if (tid == 0)
        __hip_atomic_fetch_add(&cnt[i], 1, __ATOMIC_RELAXED, __HIP_MEMORY_SCOPE_AGENT);

    // --- fused Hebbian update (off critical path): rbar in-place into xs ---
#pragma unroll
    for (int s = 0; s < 8; s++) {
        int t = tid + s * 256;
        int xi = xidx(t >> 9, t & 511);
        xs[xi] = OMA * rbar0[(size_t)i * TT + t] + ALPH * xs[xi];
    }
    __syncthreads();

    const float e_own = OMA * eb0v + ALPH * mis;
    const int lane = tid & 63, qb = lane & ~3;
    const float e0 = __shfl(e_own, qb + 0);
    const float e1 = __shfl(e_own, qb + 1);
    const float e2 = __shfl(e_own, qb + 2);
    const float e3 = __shfl(e_own, qb + 3);

#pragma unroll
    for (int s = 0; s < 128; s++) {
        const int m = mq * 128 + s;
        const int xo = mq * QSTR + s;
        const float dw = e0 * xs[xo] + e1 * xs[BSTR + xo] + e2 * xs[2 * BSTR + xo] + e3 * xs[3 * BSTR + xo];
        outW[(((size_t)i * NN + m) * NN) + kg] = w[s] + LRQ * dw;
    }

    // --- F partial (deterministic per-block double) ---
    double p = (double)mis * (double)mis;
#pragma unroll
    for (int off = 32; off; off >>= 1) p += __shfl_xor(p, off);
    if (lane == 0) ps[tid >> 6] = p;
    __syncthreads();
    if (tid == 0) fpart[(size_t)(c0 / CH) * (CH * SLC) + blockIdx.x] = ps[0] + ps[1] + ps[2] + ps[3];
}

// ---------------- final F reduction ----------------
__global__ __launch_bounds__(256) void k_fin(const double* __restrict__ fpart,
                                             float* __restrict__ outF) {
    __shared__ double ps[256];
    double s = 0.0;
    for (int idx = threadIdx.x; idx < NCH * CH * SLC; idx += 256) s += fpart[idx];
    ps[threadIdx.x] = s;
    __syncthreads();
    for (int st = 128; st; st >>= 1) {
        if (threadIdx.x < st) ps[threadIdx.x] += ps[threadIdx.x + st];
        __syncthreads();
    }
    if (threadIdx.x == 0) outF[0] = (float)(ps[0] / 614400.0);
}

extern "C" void kernel_launch(void* const* d_in, const int* in_sizes, int n_in,
                              void* d_out, int out_size, void* d_ws, size_t ws_size,
                              hipStream_t stream) {
    const float* v_s0  = (const float*)d_in[0];
    const float* v_b0  = (const float*)d_in[1];
    const float* v_a0  = (const float*)d_in[2];
    const float* rbar0 = (const float*)d_in[3];
    const float* ebar0 = (const float*)d_in[4];
    const float* W     = (const float*)d_in[5];
    const float* A     = (const float*)d_in[6];
    const float* inp   = (const float*)d_in[7];
    const float* noise = (const float*)d_in[8];

    float* out_sp = (float*)d_out;                 // [300,4,512]
    float* out_W  = out_sp + 614400;               // [300,512,512]
    float* out_F  = out_sp + 79257600;             // scalar

    char* ws = (char*)d_ws;
    float* v_init = (float*)ws;                        // 614400 f
    float* X      = v_init + 614400;                   // 614400 f
    float* delta  = X + 614400;                        // 614400 f
    int*   cnt    = (int*)(ws + 3ull * 2457600);       // 300 ints
    double* fpart = (double*)(ws + 7374000);           // 2400 doubles

    hipMemsetAsync(cnt, 0, NR * sizeof(int), stream);
    k_init<<<600, 256, 0, stream>>>(v_s0, noise, v_init);
    k_base<<<160, 256, 0, stream>>>(A, v_init, inp, X);
    for (int c = 0; c < NCH; c++) {
        int c0 = c * CH;
        if (c) k_pre<<<CH * SLC, 256, 0, stream>>>(A, delta, X, c0);
        k_chain<<<CH * SLC, 256, 0, stream>>>(W, v_b0, v_a0, A, v_init, X,
                                              rbar0, ebar0, delta, cnt,
                                              out_sp, out_W, fpart, c0);
    }
    k_fin<<<1, 256, 0, stream>>>(fpart, out_F);
}

// Round 3
// 1875.591 us; speedup vs baseline: 1.7571x; 1.2377x over previous
//
#include <hip/hip_runtime.h>

// Problem constants
#define NR   300
#define NB   4
#define NN   512
#define TT   2048          // NB*NN
#define CH   30            // regions per chunk
#define NCH  10            // chunks
#define SLC  8             // k-slice blocks per region (64 k each)

#define TAU   0.8f
#define OMT   0.2f         // 1-TAU
#define ALPH  0.05f
#define OMA   0.95f
#define LRQ   5.0e-6f      // HEBB_LR / B = 2e-5/4
#define NSC   0.02f

// padded LDS x layout: [b][quarter][128] with quarter stride 136 floats
#define QSTR 136
#define BSTR 544           // 4*136
__device__ __forceinline__ int xidx(int b, int n) {
    return b * BSTR + (n >> 7) * QSTR + (n & 127);
}

// ---------------- v_init = v_s0 + 0.02*noise ----------------
__global__ __launch_bounds__(256) void k_init(const float* __restrict__ vs0,
                                              const float* __restrict__ noise,
                                              float* __restrict__ v_init) {
    int idx = blockIdx.x * 256 + threadIdx.x;           // float4 index
    const float4* a = (const float4*)vs0;
    const float4* b = (const float4*)noise;
    float4* o = (float4*)v_init;
    float4 va = a[idx], vb = b[idx];
    float4 r;
    r.x = va.x + NSC * vb.x; r.y = va.y + NSC * vb.y;
    r.z = va.z + NSC * vb.z; r.w = va.w + NSC * vb.w;
    o[idx] = r;
}

// ---------------- X[i,t] = inp[i,t] + sum_j A[j,i]*v_init[j,t] ----------------
// grid = 300 regions x 2 t-halves; float4 per thread. Same per-t FMA order as before.
__global__ __launch_bounds__(256) void k_base(const float* __restrict__ A,
                                              const float* __restrict__ v_init,
                                              const float* __restrict__ inp,
                                              float* __restrict__ X) {
    const int i  = blockIdx.x >> 1;
    const int t4 = (blockIdx.x & 1) * 256 + threadIdx.x;   // float4 index 0..511
    float4 acc = make_float4(0.f, 0.f, 0.f, 0.f);
    for (int j = 0; j < NR; j++) {
        const float a = A[(size_t)j * NR + i];
        const float4 v = ((const float4*)(v_init + (size_t)j * TT))[t4];
        acc.x = fmaf(a, v.x, acc.x); acc.y = fmaf(a, v.y, acc.y);
        acc.z = fmaf(a, v.z, acc.z); acc.w = fmaf(a, v.w, acc.w);
    }
    const float4 p = ((const float4*)(inp + (size_t)i * TT))[t4];
    float4 r;
    r.x = p.x + acc.x; r.y = p.y + acc.y; r.z = p.z + acc.z; r.w = p.w + acc.w;
    ((float4*)(X + (size_t)i * TT))[t4] = r;
}

// ---------------- cross-chunk delta fold: X[i] += sum_{j<c0} A[j,i]*delta[j] ----------------
// grid = 30 regions x 2 t-halves; float4. Same per-t order (X init, sequential j FMA).
__global__ __launch_bounds__(256) void k_pre(const float* __restrict__ A,
                                             const float* __restrict__ delta,
                                             float* __restrict__ X, int c0) {
    const int i  = c0 + (blockIdx.x >> 1);
    const int t4 = (blockIdx.x & 1) * 256 + threadIdx.x;
    float4 acc = ((const float4*)(X + (size_t)i * TT))[t4];
    for (int j = 0; j < c0; j++) {
        const float a = A[(size_t)j * NR + i];
        const float4 d = ((const float4*)(delta + (size_t)j * TT))[t4];
        acc.x = fmaf(a, d.x, acc.x); acc.y = fmaf(a, d.y, acc.y);
        acc.z = fmaf(a, d.z, acc.z); acc.w = fmaf(a, d.w, acc.w);
    }
    ((float4*)(X + (size_t)i * TT))[t4] = acc;
}

// ---------------- sequential chain for one chunk (+fused Hebbian W update) ----------------
// grid = CH*SLC = 240 blocks (all resident; spin-safe).
// Sync: per-reader private flag lines (flagmat[reader_row*16 + slice]), monotonic values j+1.
// Publisher: drain deltas (vmcnt0+barrier), then fire-and-forget sc1 stores to each
// remaining reader's private line. Readers: per-wave independent poll (min over 8 slots),
// register-accumulated gather, one barrier before the GEMM.
__global__ __launch_bounds__(256, 1) void k_chain(
    const float* __restrict__ W,   const float* __restrict__ vb0,
    const float* __restrict__ va0, const float* __restrict__ A,
    const float* __restrict__ v_init, const float* __restrict__ X,
    const float* __restrict__ rbar0,  const float* __restrict__ ebar0,
    float* __restrict__ delta, int* __restrict__ flagmat,
    float* __restrict__ out_sp, float* __restrict__ outW,
    double* __restrict__ fpart, int c0) {

    const int tid  = threadIdx.x;
    const int lane = tid & 63;
    const int rb   = blockIdx.x >> 3;
    const int q    = blockIdx.x & 7;
    const int i    = c0 + rb;
    const int k_local = tid >> 2;        // 0..63
    const int mq   = tid & 3;            // m-quarter AND b-lane
    const int kg   = q * 64 + k_local;   // global output column

    __shared__ __align__(16) float xs[4 * BSTR];
    __shared__ float As[CH];
    __shared__ double ps[4];

    // --- preload per-thread state scalars (off critical path) ---
    const size_t base = (size_t)i * TT + (size_t)mq * NN + kg;
    const float vb0v = vb0[base];
    const float va0v = va0[base];
    const float vsi  = v_init[base];
    const float eb0v = ebar0[base];

    if (tid < CH) As[tid] = A[(size_t)(c0 + tid) * NR + i];
    __syncthreads();   // As visible to all waves before barrier-free gather

    // --- preload W slice into registers: w[s] = W[i][mq*128+s][kg] ---
    float w[128];
    const float* Wp = W + (((size_t)i * NN + (size_t)mq * 128) * NN) + kg;
#pragma unroll
    for (int s = 0; s < 128; s++) w[s] = Wp[(size_t)s * NN];

    // --- x accumulator in registers, init from X ---
    float racc[8];
#pragma unroll
    for (int s = 0; s < 8; s++) racc[s] = X[(size_t)i * TT + tid + s * 256];

    // --- gather: per-wave independent poll + register FMA (same value chain as R2) ---
    const int row = rb * 16;
    int ready = c0;    // regions with index < ready are fully published
    for (int j = c0; j < i; j++) {
        while (ready <= j) {
            int v = (lane < 8)
                ? __hip_atomic_load(&flagmat[row + lane], __ATOMIC_RELAXED, __HIP_MEMORY_SCOPE_AGENT)
                : 0x7fffffff;
            int m = v;
            m = min(m, __shfl_xor(m, 1));
            m = min(m, __shfl_xor(m, 2));
            m = min(m, __shfl_xor(m, 4));
            ready = __shfl(m, 0);
        }
        asm volatile("" ::: "memory");
        const float a = As[j - c0];
        const float* dp = delta + (size_t)j * TT;
#pragma unroll
        for (int s = 0; s < 8; s++) {
            float dv = __hip_atomic_load(&dp[tid + s * 256], __ATOMIC_RELAXED, __HIP_MEMORY_SCOPE_AGENT);
            racc[s] = fmaf(a, dv, racc[s]);
        }
    }

    // --- publish x into LDS, one barrier ---
#pragma unroll
    for (int s = 0; s < 8; s++) {
        int t = tid + s * 256;
        xs[xidx(t >> 9, t & 511)] = racc[s];
    }
    __syncthreads();

    // --- GEMM: pred[b][kg] = sum_m x[b][m]*W[m][kg]; per-lane order identical to R2 ---
    float acc0 = 0.f, acc1 = 0.f, acc2 = 0.f, acc3 = 0.f;
#pragma unroll
    for (int s4 = 0; s4 < 32; s4++) {
        const int mb = mq * QSTR + s4 * 4;
        float4 x0 = *(const float4*)&xs[mb];
        float4 x1 = *(const float4*)&xs[BSTR + mb];
        float4 x2 = *(const float4*)&xs[2 * BSTR + mb];
        float4 x3 = *(const float4*)&xs[3 * BSTR + mb];
        const float w0 = w[s4 * 4], w1 = w[s4 * 4 + 1], w2 = w[s4 * 4 + 2], w3 = w[s4 * 4 + 3];
        acc0 += x0.x * w0 + x0.y * w1 + x0.z * w2 + x0.w * w3;
        acc1 += x1.x * w0 + x1.y * w1 + x1.z * w2 + x1.w * w3;
        acc2 += x2.x * w0 + x2.y * w1 + x2.z * w2 + x2.w * w3;
        acc3 += x3.x * w0 + x3.y * w1 + x3.z * w2 + x3.w * w3;
    }
    acc0 += __shfl_xor(acc0, 1); acc0 += __shfl_xor(acc0, 2);
    acc1 += __shfl_xor(acc1, 1); acc1 += __shfl_xor(acc1, 2);
    acc2 += __shfl_xor(acc2, 1); acc2 += __shfl_xor(acc2, 2);
    acc3 += __shfl_xor(acc3, 1); acc3 += __shfl_xor(acc3, 2);
    const float pred = (mq == 0) ? acc0 : (mq == 1) ? acc1 : (mq == 2) ? acc2 : acc3;

    // --- elementwise state update for (b=mq, n=kg) ---
    const float vb  = TAU * vb0v + OMT * pred;
    const float va  = TAU * va0v;
    const float vs  = TAU * vsi + OMT * (vb - va);
    out_sp[base] = (vs > 0.f) ? 1.f : 0.f;
    __hip_atomic_store(&delta[base], vs - vsi, __ATOMIC_RELAXED, __HIP_MEMORY_SCOPE_AGENT);
    const float mis = vs - vb;

    // --- publish: drain delta stores, then broadcast flags to reader-private lines ---
    asm volatile("s_waitcnt vmcnt(0)" ::: "memory");
    __syncthreads();
    {
        const int nrd = c0 + CH - 1 - i;          // remaining readers in chunk
        if (tid < nrd) {
            const int r = i + 1 + tid;
            __hip_atomic_store(&flagmat[(r - c0) * 16 + q], i + 1,
                               __ATOMIC_RELAXED, __HIP_MEMORY_SCOPE_AGENT);
        }
    }

    // --- fused Hebbian update (off critical path): rbar in-place into xs ---
#pragma unroll
    for (int s = 0; s < 8; s++) {
        int t = tid + s * 256;
        int xi = xidx(t >> 9, t & 511);
        xs[xi] = OMA * rbar0[(size_t)i * TT + t] + ALPH * xs[xi];
    }
    __syncthreads();

    const float e_own = OMA * eb0v + ALPH * mis;
    const int qb = lane & ~3;
    const float e0 = __shfl(e_own, qb + 0);
    const float e1 = __shfl(e_own, qb + 1);
    const float e2 = __shfl(e_own, qb + 2);
    const float e3 = __shfl(e_own, qb + 3);

#pragma unroll
    for (int s = 0; s < 128; s++) {
        const int m = mq * 128 + s;
        const int xo = mq * QSTR + s;
        const float dw = e0 * xs[xo] + e1 * xs[BSTR + xo] + e2 * xs[2 * BSTR + xo] + e3 * xs[3 * BSTR + xo];
        outW[(((size_t)i * NN + m) * NN) + kg] = w[s] + LRQ * dw;
    }

    // --- F partial (deterministic per-block double) ---
    double p = (double)mis * (double)mis;
#pragma unroll
    for (int off = 32; off; off >>= 1) p += __shfl_xor(p, off);
    if (lane == 0) ps[tid >> 6] = p;
    __syncthreads();
    if (tid == 0) fpart[(size_t)(c0 / CH) * (CH * SLC) + blockIdx.x] = ps[0] + ps[1] + ps[2] + ps[3];
}

// ---------------- final F reduction ----------------
__global__ __launch_bounds__(256) void k_fin(const double* __restrict__ fpart,
                                             float* __restrict__ outF) {
    __shared__ double ps[256];
    double s = 0.0;
    for (int idx = threadIdx.x; idx < NCH * CH * SLC; idx += 256) s += fpart[idx];
    ps[threadIdx.x] = s;
    __syncthreads();
    for (int st = 128; st; st >>= 1) {
        if (threadIdx.x < st) ps[threadIdx.x] += ps[threadIdx.x + st];
        __syncthreads();
    }
    if (threadIdx.x == 0) outF[0] = (float)(ps[0] / 614400.0);
}

extern "C" void kernel_launch(void* const* d_in, const int* in_sizes, int n_in,
                              void* d_out, int out_size, void* d_ws, size_t ws_size,
                              hipStream_t stream) {
    const float* v_s0  = (const float*)d_in[0];
    const float* v_b0  = (const float*)d_in[1];
    const float* v_a0  = (const float*)d_in[2];
    const float* rbar0 = (const float*)d_in[3];
    const float* ebar0 = (const float*)d_in[4];
    const float* W     = (const float*)d_in[5];
    const float* A     = (const float*)d_in[6];
    const float* inp   = (const float*)d_in[7];
    const float* noise = (const float*)d_in[8];

    float* out_sp = (float*)d_out;                 // [300,4,512]
    float* out_W  = out_sp + 614400;               // [300,512,512]
    float* out_F  = out_sp + 79257600;             // scalar

    char* ws = (char*)d_ws;
    float* v_init  = (float*)ws;                       // 614400 f
    float* X       = v_init + 614400;                  // 614400 f
    float* delta   = X + 614400;                       // 614400 f
    int*   flagmat = (int*)(ws + 7372800);             // 30 rows x 16 ints (64B lines)
    double* fpart  = (double*)(ws + 7377920);          // 2400 doubles

    hipMemsetAsync(flagmat, 0, CH * 16 * sizeof(int), stream);
    k_init<<<600, 256, 0, stream>>>(v_s0, noise, v_init);
    k_base<<<600, 256, 0, stream>>>(A, v_init, inp, X);
    for (int c = 0; c < NCH; c++) {
        int c0 = c * CH;
        if (c) k_pre<<<CH * 2, 256, 0, stream>>>(A, delta, X, c0);
        k_chain<<<CH * SLC, 256, 0, stream>>>(W, v_b0, v_a0, A, v_init, X,
                                              rbar0, ebar0, delta, flagmat,
                                              out_sp, out_W, fpart, c0);
    }
    k_fin<<<1, 256, 0, stream>>>(fpart, out_F);
}

// Round 4
// 1857.434 us; speedup vs baseline: 1.7742x; 1.0098x over previous
//
#include <hip/hip_runtime.h>

// Problem constants
#define NR   300
#define NB   4
#define NN   512
#define TT   2048          // NB*NN
#define CH   30            // regions per persistent-block stride
#define NCH  10            // regions per block
#define SLC  8             // k-slice blocks per region (64 k each)

#define TAU   0.8f
#define OMT   0.2f         // 1-TAU
#define ALPH  0.05f
#define OMA   0.95f
#define LRQ   5.0e-6f      // HEBB_LR / B = 2e-5/4
#define NSC   0.02f

// padded LDS x layout: [b][quarter][128] with quarter stride 136 floats
#define QSTR 136
#define BSTR 544           // 4*136
__device__ __forceinline__ int xidx(int b, int n) {
    return b * BSTR + (n >> 7) * QSTR + (n & 127);
}

// ---------------- v_init = v_s0 + 0.02*noise ----------------
__global__ __launch_bounds__(256) void k_init(const float* __restrict__ vs0,
                                              const float* __restrict__ noise,
                                              float* __restrict__ v_init) {
    int idx = blockIdx.x * 256 + threadIdx.x;           // float4 index
    const float4* a = (const float4*)vs0;
    const float4* b = (const float4*)noise;
    float4* o = (float4*)v_init;
    float4 va = a[idx], vb = b[idx];
    float4 r;
    r.x = va.x + NSC * vb.x; r.y = va.y + NSC * vb.y;
    r.z = va.z + NSC * vb.z; r.w = va.w + NSC * vb.w;
    o[idx] = r;
}

// ---------------- X[i,t] = inp[i,t] + sum_j A[j,i]*v_init[j,t] ----------------
// 5 regions per block (v_init reuse): grid = 60 groups x 2 t-halves = 120 blocks.
// Per-element fmaf chain over ascending j -> bit-identical to previous rounds.
__global__ __launch_bounds__(256) void k_base(const float* __restrict__ A,
                                              const float* __restrict__ v_init,
                                              const float* __restrict__ inp,
                                              float* __restrict__ X) {
    const int i0 = (blockIdx.x >> 1) * 5;
    const int t4 = (blockIdx.x & 1) * 256 + threadIdx.x;   // float4 index 0..511
    float4 acc[5];
#pragma unroll
    for (int g = 0; g < 5; g++) acc[g] = make_float4(0.f, 0.f, 0.f, 0.f);
    for (int j = 0; j < NR; j++) {
        const float4 v = ((const float4*)(v_init + (size_t)j * TT))[t4];
#pragma unroll
        for (int g = 0; g < 5; g++) {
            const float a = A[(size_t)j * NR + i0 + g];
            acc[g].x = fmaf(a, v.x, acc[g].x); acc[g].y = fmaf(a, v.y, acc[g].y);
            acc[g].z = fmaf(a, v.z, acc[g].z); acc[g].w = fmaf(a, v.w, acc[g].w);
        }
    }
#pragma unroll
    for (int g = 0; g < 5; g++) {
        const float4 p = ((const float4*)(inp + (size_t)(i0 + g) * TT))[t4];
        float4 r;
        r.x = p.x + acc[g].x; r.y = p.y + acc[g].y;
        r.z = p.z + acc[g].z; r.w = p.w + acc[g].w;
        ((float4*)(X + (size_t)(i0 + g) * TT))[t4] = r;
    }
}

// ---------------- persistent chain: whole 300-region sequence in ONE kernel ----------------
// grid = 240 blocks (1/CU guaranteed resident; spin-safe). Block (rb,q) handles
// regions rb, rb+30, ..., rb+270 in order. All j<i deltas gathered per region
// (base-X then ascending-j fmaf chain -> bit-identical to chunked version).
// Flags: flagmat[300 rows][32 slots, 128B rows]. Publisher region j, slice q,
// wave w: after per-wave vmcnt(0) drain, stores j+1 into slot (q*4+w) of every
// row j+1..299 (fire-and-forget, no RMW, no block barrier on publish path).
// Reader for region i: min over row i's 32 slots (monotone-causal; transient
// regressions are safe because min only delays, never falsely releases).
__global__ __launch_bounds__(256, 1) void k_chain(
    const float* __restrict__ W,   const float* __restrict__ vb0,
    const float* __restrict__ va0, const float* __restrict__ A,
    const float* __restrict__ v_init, const float* __restrict__ X,
    const float* __restrict__ rbar0,  const float* __restrict__ ebar0,
    float* __restrict__ delta, int* __restrict__ flagmat,
    float* __restrict__ out_sp, float* __restrict__ outW,
    double* __restrict__ fpart) {

    const int tid  = threadIdx.x;
    const int lane = tid & 63;
    const int wv   = tid >> 6;
    const int rb   = blockIdx.x >> 3;
    const int q    = blockIdx.x & 7;
    const int k_local = tid >> 2;        // 0..63
    const int mq   = tid & 3;            // m-quarter AND b-lane
    const int kg   = q * 64 + k_local;   // global output column

    __shared__ __align__(16) float xs[4 * BSTR];
    __shared__ double ps[4];

    for (int c = 0; c < NCH; c++) {
        const int i = rb + CH * c;
        // Everything from here to the poll loop runs in this block's idle
        // window (~29 chain steps ahead of its turn): W preload, state
        // scalars, X init, and the gather of long-published deltas.
        const size_t base = (size_t)i * TT + (size_t)mq * NN + kg;
        const float vb0v = vb0[base];
        const float va0v = va0[base];
        const float vsi  = v_init[base];
        const float eb0v = ebar0[base];

        float w[128];
        const float* Wp = W + (((size_t)i * NN + (size_t)mq * 128) * NN) + kg;
#pragma unroll
        for (int s = 0; s < 128; s++) w[s] = Wp[(size_t)s * NN];

        float racc[8];
#pragma unroll
        for (int s = 0; s < 8; s++) racc[s] = X[(size_t)i * TT + tid + s * 256];

        int ready = 0;
        for (int j = 0; j < i; j++) {
            while (ready <= j) {
                int v = (lane < 32)
                    ? __hip_atomic_load(&flagmat[i * 32 + lane], __ATOMIC_RELAXED, __HIP_MEMORY_SCOPE_AGENT)
                    : 0x7fffffff;
                v = min(v, __shfl_xor(v, 1));
                v = min(v, __shfl_xor(v, 2));
                v = min(v, __shfl_xor(v, 4));
                v = min(v, __shfl_xor(v, 8));
                v = min(v, __shfl_xor(v, 16));
                ready = __shfl(v, 0);
            }
            asm volatile("" ::: "memory");
            const float a = A[(size_t)j * NR + i];
            const float* dp = delta + (size_t)j * TT;
#pragma unroll
            for (int s = 0; s < 8; s++) {
                float dv = __hip_atomic_load(&dp[tid + s * 256], __ATOMIC_RELAXED, __HIP_MEMORY_SCOPE_AGENT);
                racc[s] = fmaf(a, dv, racc[s]);
            }
        }

        // --- publish x into LDS, one barrier ---
#pragma unroll
        for (int s = 0; s < 8; s++) {
            int t = tid + s * 256;
            xs[xidx(t >> 9, t & 511)] = racc[s];
        }
        __syncthreads();

        // --- GEMM: pred[b][kg] = sum_m x[b][m]*W[m][kg]; chains identical to R3 ---
        float acc0 = 0.f, acc1 = 0.f, acc2 = 0.f, acc3 = 0.f;
#pragma unroll
        for (int s4 = 0; s4 < 32; s4++) {
            const int mb = mq * QSTR + s4 * 4;
            float4 x0 = *(const float4*)&xs[mb];
            float4 x1 = *(const float4*)&xs[BSTR + mb];
            float4 x2 = *(const float4*)&xs[2 * BSTR + mb];
            float4 x3 = *(const float4*)&xs[3 * BSTR + mb];
            const float w0 = w[s4 * 4], w1 = w[s4 * 4 + 1], w2 = w[s4 * 4 + 2], w3 = w[s4 * 4 + 3];
            acc0 += x0.x * w0 + x0.y * w1 + x0.z * w2 + x0.w * w3;
            acc1 += x1.x * w0 + x1.y * w1 + x1.z * w2 + x1.w * w3;
            acc2 += x2.x * w0 + x2.y * w1 + x2.z * w2 + x2.w * w3;
            acc3 += x3.x * w0 + x3.y * w1 + x3.z * w2 + x3.w * w3;
        }
        acc0 += __shfl_xor(acc0, 1); acc0 += __shfl_xor(acc0, 2);
        acc1 += __shfl_xor(acc1, 1); acc1 += __shfl_xor(acc1, 2);
        acc2 += __shfl_xor(acc2, 1); acc2 += __shfl_xor(acc2, 2);
        acc3 += __shfl_xor(acc3, 1); acc3 += __shfl_xor(acc3, 2);
        const float pred = (mq == 0) ? acc0 : (mq == 1) ? acc1 : (mq == 2) ? acc2 : acc3;

        // --- elementwise state update for (b=mq, n=kg) ---
        const float vb  = TAU * vb0v + OMT * pred;
        const float va  = TAU * va0v;
        const float vs  = TAU * vsi + OMT * (vb - va);
        out_sp[base] = (vs > 0.f) ? 1.f : 0.f;
        __hip_atomic_store(&delta[base], vs - vsi, __ATOMIC_RELAXED, __HIP_MEMORY_SCOPE_AGENT);
        const float mis = vs - vb;

        // --- per-wave publish: drain own stores, broadcast flags to later rows ---
        asm volatile("s_waitcnt vmcnt(0)" ::: "memory");
        {
            const int slot = (q << 2) + wv;
            for (int r = i + 1 + lane; r < NR; r += 64)
                __hip_atomic_store(&flagmat[r * 32 + slot], i + 1,
                                   __ATOMIC_RELAXED, __HIP_MEMORY_SCOPE_AGENT);
        }
        __syncthreads();   // protect xs: all GEMM reads done before rbar overwrite

        // --- fused Hebbian update (off critical path): rbar in-place into xs ---
#pragma unroll
        for (int s = 0; s < 8; s++) {
            int t = tid + s * 256;
            int xi = xidx(t >> 9, t & 511);
            xs[xi] = OMA * rbar0[(size_t)i * TT + t] + ALPH * xs[xi];
        }
        __syncthreads();

        const float e_own = OMA * eb0v + ALPH * mis;
        const int qb = lane & ~3;
        const float e0 = __shfl(e_own, qb + 0);
        const float e1 = __shfl(e_own, qb + 1);
        const float e2 = __shfl(e_own, qb + 2);
        const float e3 = __shfl(e_own, qb + 3);

#pragma unroll
        for (int s = 0; s < 128; s++) {
            const int m = mq * 128 + s;
            const int xo = mq * QSTR + s;
            const float dw = e0 * xs[xo] + e1 * xs[BSTR + xo] + e2 * xs[2 * BSTR + xo] + e3 * xs[3 * BSTR + xo];
            outW[(((size_t)i * NN + m) * NN) + kg] = w[s] + LRQ * dw;
        }

        // --- F partial (deterministic per-block double) ---
        double p = (double)mis * (double)mis;
#pragma unroll
        for (int off = 32; off; off >>= 1) p += __shfl_xor(p, off);
        if (lane == 0) ps[wv] = p;
        __syncthreads();
        if (tid == 0) fpart[(size_t)i * SLC + q] = ps[0] + ps[1] + ps[2] + ps[3];
        __syncthreads();   // ps consumed before next iteration rewrites it
    }
}

// ---------------- final F reduction ----------------
__global__ __launch_bounds__(256) void k_fin(const double* __restrict__ fpart,
                                             float* __restrict__ outF) {
    __shared__ double ps[256];
    double s = 0.0;
    for (int idx = threadIdx.x; idx < NR * SLC; idx += 256) s += fpart[idx];
    ps[threadIdx.x] = s;
    __syncthreads();
    for (int st = 128; st; st >>= 1) {
        if (threadIdx.x < st) ps[threadIdx.x] += ps[threadIdx.x + st];
        __syncthreads();
    }
    if (threadIdx.x == 0) outF[0] = (float)(ps[0] / 614400.0);
}

extern "C" void kernel_launch(void* const* d_in, const int* in_sizes, int n_in,
                              void* d_out, int out_size, void* d_ws, size_t ws_size,
                              hipStream_t stream) {
    const float* v_s0  = (const float*)d_in[0];
    const float* v_b0  = (const float*)d_in[1];
    const float* v_a0  = (const float*)d_in[2];
    const float* rbar0 = (const float*)d_in[3];
    const float* ebar0 = (const float*)d_in[4];
    const float* W     = (const float*)d_in[5];
    const float* A     = (const float*)d_in[6];
    const float* inp   = (const float*)d_in[7];
    const float* noise = (const float*)d_in[8];

    float* out_sp = (float*)d_out;                 // [300,4,512]
    float* out_W  = out_sp + 614400;               // [300,512,512]
    float* out_F  = out_sp + 79257600;             // scalar

    char* ws = (char*)d_ws;
    float* v_init  = (float*)ws;                       // 614400 f
    float* X       = v_init + 614400;                  // 614400 f
    float* delta   = X + 614400;                       // 614400 f
    int*   flagmat = (int*)(ws + 7372800);             // 300 rows x 32 ints (128B rows)
    double* fpart  = (double*)(ws + 7411200);          // 2400 doubles

    hipMemsetAsync(flagmat, 0, NR * 32 * sizeof(int), stream);
    k_init<<<600, 256, 0, stream>>>(v_s0, noise, v_init);
    k_base<<<120, 256, 0, stream>>>(A, v_init, inp, X);
    k_chain<<<CH * SLC, 256, 0, stream>>>(W, v_b0, v_a0, A, v_init, X,
                                          rbar0, ebar0, delta, flagmat,
                                          out_sp, out_W, fpart);
    k_fin<<<1, 256, 0, stream>>>(fpart, out_F);
}

// Round 5
// 1799.716 us; speedup vs baseline: 1.8311x; 1.0321x over previous
//
#include <hip/hip_runtime.h>

// Problem constants
#define NR   300
#define NB   4
#define NN   512
#define TT   2048          // NB*NN
#define CH   30            // region-row stride (persistent blocks)
#define NCH  10            // regions per block
#define SLC  8             // k-slice blocks per region (64 k each)

#define TAU   0.8f
#define OMT   0.2f         // 1-TAU
#define ALPH  0.05f
#define OMA   0.95f
#define LRQ   5.0e-6f      // HEBB_LR / B = 2e-5/4
#define NSC   0.02f

// padded LDS x layout: [b][quarter][128] with quarter stride 136 floats
#define QSTR 136
#define BSTR 544           // 4*136
__device__ __forceinline__ int xidx(int b, int n) {
    return b * BSTR + (n >> 7) * QSTR + (n & 127);
}

// ---------------- v_init = v_s0 + 0.02*noise ----------------
__global__ __launch_bounds__(256) void k_init(const float* __restrict__ vs0,
                                              const float* __restrict__ noise,
                                              float* __restrict__ v_init) {
    int idx = blockIdx.x * 256 + threadIdx.x;           // float4 index
    const float4* a = (const float4*)vs0;
    const float4* b = (const float4*)noise;
    float4* o = (float4*)v_init;
    float4 va = a[idx], vb = b[idx];
    float4 r;
    r.x = va.x + NSC * vb.x; r.y = va.y + NSC * vb.y;
    r.z = va.z + NSC * vb.z; r.w = va.w + NSC * vb.w;
    o[idx] = r;
}

// ---------------- X[i,t] = inp[i,t] + sum_j A[j,i]*v_init[j,t] ----------------
__global__ __launch_bounds__(256) void k_base(const float* __restrict__ A,
                                              const float* __restrict__ v_init,
                                              const float* __restrict__ inp,
                                              float* __restrict__ X) {
    const int i0 = (blockIdx.x >> 1) * 5;
    const int t4 = (blockIdx.x & 1) * 256 + threadIdx.x;   // float4 index 0..511
    float4 acc[5];
#pragma unroll
    for (int g = 0; g < 5; g++) acc[g] = make_float4(0.f, 0.f, 0.f, 0.f);
    for (int j = 0; j < NR; j++) {
        const float4 v = ((const float4*)(v_init + (size_t)j * TT))[t4];
#pragma unroll
        for (int g = 0; g < 5; g++) {
            const float a = A[(size_t)j * NR + i0 + g];
            acc[g].x = fmaf(a, v.x, acc[g].x); acc[g].y = fmaf(a, v.y, acc[g].y);
            acc[g].z = fmaf(a, v.z, acc[g].z); acc[g].w = fmaf(a, v.w, acc[g].w);
        }
    }
#pragma unroll
    for (int g = 0; g < 5; g++) {
        const float4 p = ((const float4*)(inp + (size_t)(i0 + g) * TT))[t4];
        float4 r;
        r.x = p.x + acc[g].x; r.y = p.y + acc[g].y;
        r.z = p.z + acc[g].z; r.w = p.w + acc[g].w;
        ((float4*)(X + (size_t)(i0 + g) * TT))[t4] = r;
    }
}

// ---------------- persistent chain: whole 300-region sequence in ONE kernel ----------------
// grid = 240 blocks (1/CU resident; spin-safe). Block (rb,q) handles regions
// rb, rb+30, ..., rb+270. Sync: flagmat[300 rows][32 slots, 128B rows], monotone
// values j+1, per-wave sc1 publish after per-wave vmcnt(0) drain of the sc1
// delta store. Gather: poll once -> bulk-accumulate all newly-ready j with
// PLAIN pipelined float4 loads (safe: lines first-touched only after flag,
// sc1 stores put fresh data at IC, dispatch-boundary invalidate clears stale L2).
__global__ __launch_bounds__(256, 1) void k_chain(
    const float* __restrict__ W,   const float* __restrict__ vb0,
    const float* __restrict__ va0, const float* __restrict__ A,
    const float* __restrict__ v_init, const float* __restrict__ X,
    const float* __restrict__ rbar0,  const float* __restrict__ ebar0,
    float* __restrict__ delta, int* __restrict__ flagmat,
    float* __restrict__ out_sp, float* __restrict__ outW,
    double* __restrict__ fpart) {

    const int tid  = threadIdx.x;
    const int lane = tid & 63;
    const int wv   = tid >> 6;
    const int rb   = blockIdx.x >> 3;
    const int q    = blockIdx.x & 3 ? (blockIdx.x & 7) : (blockIdx.x & 7); // q = bid&7
    const int qq   = blockIdx.x & 7;
    const int k_local = tid >> 2;        // 0..63
    const int mq   = tid & 3;            // m-quarter AND b-lane
    const int kg   = qq * 64 + k_local;  // global output column

    __shared__ __align__(16) float xs[4 * BSTR];
    __shared__ double ps[4];

    const float4* __restrict__ d4 = (const float4*)delta;

    for (int c = 0; c < NCH; c++) {
        const int i = rb + CH * c;
        // idle-window work: state scalars, W preload, X init, bulk gather
        const size_t base = (size_t)i * TT + (size_t)mq * NN + kg;
        const float vb0v = vb0[base];
        const float va0v = va0[base];
        const float vsi  = v_init[base];
        const float eb0v = ebar0[base];

        float w[128];
        const float* Wp = W + (((size_t)i * NN + (size_t)mq * 128) * NN) + kg;
#pragma unroll
        for (int s = 0; s < 128; s++) w[s] = Wp[(size_t)s * NN];

        // x accumulators: thread owns elements [4*tid,4*tid+4) and [4*tid+1024,+4)
        float4 r0 = ((const float4*)(X + (size_t)i * TT))[tid];
        float4 r1 = ((const float4*)(X + (size_t)i * TT))[tid + 256];

        // --- gather: poll row i, bulk-accumulate newly ready j with plain loads ---
        int jdone = 0;
        while (jdone < i) {
            int v = (lane < 32)
                ? __hip_atomic_load(&flagmat[i * 32 + lane], __ATOMIC_RELAXED, __HIP_MEMORY_SCOPE_AGENT)
                : 0x7fffffff;
            v = min(v, __shfl_xor(v, 1));
            v = min(v, __shfl_xor(v, 2));
            v = min(v, __shfl_xor(v, 4));
            v = min(v, __shfl_xor(v, 8));
            v = min(v, __shfl_xor(v, 16));
            int ready = __shfl(v, 0);
            if (ready > i) ready = i;
            if (ready > jdone) {
                asm volatile("" ::: "memory");
                for (int j = jdone; j < ready; j++) {
                    const float a = A[(size_t)j * NR + i];
                    const float4 d0 = d4[j * 512 + tid];
                    const float4 d1 = d4[j * 512 + tid + 256];
                    r0.x = fmaf(a, d0.x, r0.x); r0.y = fmaf(a, d0.y, r0.y);
                    r0.z = fmaf(a, d0.z, r0.z); r0.w = fmaf(a, d0.w, r0.w);
                    r1.x = fmaf(a, d1.x, r1.x); r1.y = fmaf(a, d1.y, r1.y);
                    r1.z = fmaf(a, d1.z, r1.z); r1.w = fmaf(a, d1.w, r1.w);
                }
                jdone = ready;
            }
        }

        // --- publish x into LDS (float4-aligned in padded layout), one barrier ---
        {
            const int e0 = 4 * tid;          // elements e0..e0+3 (same quarter)
            const int e1 = 4 * tid + 1024;
            *(float4*)&xs[xidx(e0 >> 9, e0 & 511)] = r0;
            *(float4*)&xs[xidx(e1 >> 9, e1 & 511)] = r1;
        }
        __syncthreads();

        // --- GEMM: pred[b][kg] = sum_m x[b][m]*W[m][kg]; chains identical to R4 ---
        float acc0 = 0.f, acc1 = 0.f, acc2 = 0.f, acc3 = 0.f;
#pragma unroll
        for (int s4 = 0; s4 < 32; s4++) {
            const int mb = mq * QSTR + s4 * 4;
            float4 x0 = *(const float4*)&xs[mb];
            float4 x1 = *(const float4*)&xs[BSTR + mb];
            float4 x2 = *(const float4*)&xs[2 * BSTR + mb];
            float4 x3 = *(const float4*)&xs[3 * BSTR + mb];
            const float w0 = w[s4 * 4], w1 = w[s4 * 4 + 1], w2 = w[s4 * 4 + 2], w3 = w[s4 * 4 + 3];
            acc0 += x0.x * w0 + x0.y * w1 + x0.z * w2 + x0.w * w3;
            acc1 += x1.x * w0 + x1.y * w1 + x1.z * w2 + x1.w * w3;
            acc2 += x2.x * w0 + x2.y * w1 + x2.z * w2 + x2.w * w3;
            acc3 += x3.x * w0 + x3.y * w1 + x3.z * w2 + x3.w * w3;
        }
        acc0 += __shfl_xor(acc0, 1); acc0 += __shfl_xor(acc0, 2);
        acc1 += __shfl_xor(acc1, 1); acc1 += __shfl_xor(acc1, 2);
        acc2 += __shfl_xor(acc2, 1); acc2 += __shfl_xor(acc2, 2);
        acc3 += __shfl_xor(acc3, 1); acc3 += __shfl_xor(acc3, 2);
        const float pred = (mq == 0) ? acc0 : (mq == 1) ? acc1 : (mq == 2) ? acc2 : acc3;

        // --- state update for (b=mq, n=kg); publish delta first, flags ASAP ---
        const float vb  = TAU * vb0v + OMT * pred;
        const float va  = TAU * va0v;
        const float vs  = TAU * vsi + OMT * (vb - va);
        __hip_atomic_store(&delta[base], vs - vsi, __ATOMIC_RELAXED, __HIP_MEMORY_SCOPE_AGENT);
        const float mis = vs - vb;

        asm volatile("s_waitcnt vmcnt(0)" ::: "memory");   // delta in IC
        {
            const int slot = (qq << 2) + wv;
            for (int r = i + 1 + lane; r < NR; r += 64)
                __hip_atomic_store(&flagmat[r * 32 + slot], i + 1,
                                   __ATOMIC_RELAXED, __HIP_MEMORY_SCOPE_AGENT);
        }
        out_sp[base] = (vs > 0.f) ? 1.f : 0.f;
        __syncthreads();   // protect xs: all GEMM reads done before rbar overwrite

        // --- fused Hebbian (off critical path): rbar in-place into xs, float4 ---
#pragma unroll
        for (int s = 0; s < 2; s++) {
            const int e = 4 * tid + s * 1024;
            float* xp = &xs[xidx(e >> 9, e & 511)];
            const float4 rr = ((const float4*)(rbar0 + (size_t)i * TT))[tid + s * 256];
            float4 xv = *(float4*)xp;
            xv.x = OMA * rr.x + ALPH * xv.x; xv.y = OMA * rr.y + ALPH * xv.y;
            xv.z = OMA * rr.z + ALPH * xv.z; xv.w = OMA * rr.w + ALPH * xv.w;
            *(float4*)xp = xv;
        }
        __syncthreads();

        const float e_own = OMA * eb0v + ALPH * mis;
        const int qb = lane & ~3;
        const float e0 = __shfl(e_own, qb + 0);
        const float e1 = __shfl(e_own, qb + 1);
        const float e2 = __shfl(e_own, qb + 2);
        const float e3 = __shfl(e_own, qb + 3);

#pragma unroll
        for (int s = 0; s < 128; s++) {
            const int m = mq * 128 + s;
            const int xo = mq * QSTR + s;
            const float dw = e0 * xs[xo] + e1 * xs[BSTR + xo] + e2 * xs[2 * BSTR + xo] + e3 * xs[3 * BSTR + xo];
            outW[(((size_t)i * NN + m) * NN) + kg] = w[s] + LRQ * dw;
        }

        // --- F partial (deterministic per-block double) ---
        double p = (double)mis * (double)mis;
#pragma unroll
        for (int off = 32; off; off >>= 1) p += __shfl_xor(p, off);
        if (lane == 0) ps[wv] = p;
        __syncthreads();
        if (tid == 0) fpart[(size_t)i * SLC + qq] = ps[0] + ps[1] + ps[2] + ps[3];
        __syncthreads();   // ps consumed before next iteration rewrites it
    }
}

// ---------------- final F reduction ----------------
__global__ __launch_bounds__(256) void k_fin(const double* __restrict__ fpart,
                                             float* __restrict__ outF) {
    __shared__ double ps[256];
    double s = 0.0;
    for (int idx = threadIdx.x; idx < NR * SLC; idx += 256) s += fpart[idx];
    ps[threadIdx.x] = s;
    __syncthreads();
    for (int st = 128; st; st >>= 1) {
        if (threadIdx.x < st) ps[threadIdx.x] += ps[threadIdx.x + st];
        __syncthreads();
    }
    if (threadIdx.x == 0) outF[0] = (float)(ps[0] / 614400.0);
}

extern "C" void kernel_launch(void* const* d_in, const int* in_sizes, int n_in,
                              void* d_out, int out_size, void* d_ws, size_t ws_size,
                              hipStream_t stream) {
    const float* v_s0  = (const float*)d_in[0];
    const float* v_b0  = (const float*)d_in[1];
    const float* v_a0  = (const float*)d_in[2];
    const float* rbar0 = (const float*)d_in[3];
    const float* ebar0 = (const float*)d_in[4];
    const float* W     = (const float*)d_in[5];
    const float* A     = (const float*)d_in[6];
    const float* inp   = (const float*)d_in[7];
    const float* noise = (const float*)d_in[8];

    float* out_sp = (float*)d_out;                 // [300,4,512]
    float* out_W  = out_sp + 614400;               // [300,512,512]
    float* out_F  = out_sp + 79257600;             // scalar

    char* ws = (char*)d_ws;
    float* v_init  = (float*)ws;                       // 614400 f
    float* X       = v_init + 614400;                  // 614400 f
    float* delta   = X + 614400;                       // 614400 f
    int*   flagmat = (int*)(ws + 7372800);             // 300 rows x 32 ints (128B rows)
    double* fpart  = (double*)(ws + 7411200);          // 2400 doubles

    hipMemsetAsync(flagmat, 0, NR * 32 * sizeof(int), stream);
    k_init<<<600, 256, 0, stream>>>(v_s0, noise, v_init);
    k_base<<<120, 256, 0, stream>>>(A, v_init, inp, X);
    k_chain<<<CH * SLC, 256, 0, stream>>>(W, v_b0, v_a0, A, v_init, X,
                                          rbar0, ebar0, delta, flagmat,
                                          out_sp, out_W, fpart);
    k_fin<<<1, 256, 0, stream>>>(fpart, out_F);
}

// Round 6
// 1311.959 us; speedup vs baseline: 2.5119x; 1.3718x over previous
//
#include <hip/hip_runtime.h>

// Problem constants
#define NR   300
#define NB   4
#define NN   512
#define TT   2048          // NB*NN
#define CH   30            // region-row stride (persistent blocks)
#define NCH  10            // regions per block
#define SLC  8             // k-slice blocks per region (64 k each)

#define TAU   0.8f
#define OMT   0.2f         // 1-TAU
#define ALPH  0.05f
#define OMA   0.95f
#define LRQ   5.0e-6f      // HEBB_LR / B = 2e-5/4
#define NSC   0.02f

#define SENT  0xFFFFFFFFu  // delta sentinel (negative qNaN pattern; vs-vsi is always finite)

// padded LDS x layout: [b][quarter][128] with quarter stride 136 floats
#define QSTR 136
#define BSTR 544           // 4*136
__device__ __forceinline__ int xidx(int b, int n) {
    return b * BSTR + (n >> 7) * QSTR + (n & 127);
}

// ---- sc0/sc1 (IC-coherent, L2-bypass) 16B loads; load+wait fused in ONE asm
// block so outputs are fully defined at asm end (no waitcnt/use-reorder hazard).
__device__ __forceinline__ void ld2_sc_wait(const float* p0, const float* p1,
                                            float4& a, float4& b) {
    asm volatile(
        "global_load_dwordx4 %0, %2, off sc0 sc1\n\t"
        "global_load_dwordx4 %1, %3, off sc0 sc1\n\t"
        "s_waitcnt vmcnt(0)"
        : "=&v"(a), "=&v"(b)
        : "v"(p0), "v"(p1)
        : "memory");
}

__device__ __forceinline__ void ld8_sc_wait(
        const float* p00, const float* p01, const float* p10, const float* p11,
        const float* p20, const float* p21, const float* p30, const float* p31,
        float4& a0, float4& b0, float4& a1, float4& b1,
        float4& a2, float4& b2, float4& a3, float4& b3) {
    asm volatile(
        "global_load_dwordx4 %0, %8, off sc0 sc1\n\t"
        "global_load_dwordx4 %1, %9, off sc0 sc1\n\t"
        "global_load_dwordx4 %2, %10, off sc0 sc1\n\t"
        "global_load_dwordx4 %3, %11, off sc0 sc1\n\t"
        "global_load_dwordx4 %4, %12, off sc0 sc1\n\t"
        "global_load_dwordx4 %5, %13, off sc0 sc1\n\t"
        "global_load_dwordx4 %6, %14, off sc0 sc1\n\t"
        "global_load_dwordx4 %7, %15, off sc0 sc1\n\t"
        "s_waitcnt vmcnt(0)"
        : "=&v"(a0), "=&v"(b0), "=&v"(a1), "=&v"(b1),
          "=&v"(a2), "=&v"(b2), "=&v"(a3), "=&v"(b3)
        : "v"(p00), "v"(p01), "v"(p10), "v"(p11),
          "v"(p20), "v"(p21), "v"(p30), "v"(p31)
        : "memory");
}

__device__ __forceinline__ bool ok8(const float4& a, const float4& b) {
    return __float_as_uint(a.x) != SENT && __float_as_uint(a.y) != SENT &&
           __float_as_uint(a.z) != SENT && __float_as_uint(a.w) != SENT &&
           __float_as_uint(b.x) != SENT && __float_as_uint(b.y) != SENT &&
           __float_as_uint(b.z) != SENT && __float_as_uint(b.w) != SENT;
}

// ---------------- v_init = v_s0 + 0.02*noise ----------------
__global__ __launch_bounds__(256) void k_init(const float* __restrict__ vs0,
                                              const float* __restrict__ noise,
                                              float* __restrict__ v_init) {
    int idx = blockIdx.x * 256 + threadIdx.x;           // float4 index
    const float4* a = (const float4*)vs0;
    const float4* b = (const float4*)noise;
    float4* o = (float4*)v_init;
    float4 va = a[idx], vb = b[idx];
    float4 r;
    r.x = va.x + NSC * vb.x; r.y = va.y + NSC * vb.y;
    r.z = va.z + NSC * vb.z; r.w = va.w + NSC * vb.w;
    o[idx] = r;
}

// ---------------- X[i,t] = inp[i,t] + sum_j A[j,i]*v_init[j,t] ----------------
__global__ __launch_bounds__(256) void k_base(const float* __restrict__ A,
                                              const float* __restrict__ v_init,
                                              const float* __restrict__ inp,
                                              float* __restrict__ X) {
    const int i0 = (blockIdx.x >> 1) * 5;
    const int t4 = (blockIdx.x & 1) * 256 + threadIdx.x;   // float4 index 0..511
    float4 acc[5];
#pragma unroll
    for (int g = 0; g < 5; g++) acc[g] = make_float4(0.f, 0.f, 0.f, 0.f);
    for (int j = 0; j < NR; j++) {
        const float4 v = ((const float4*)(v_init + (size_t)j * TT))[t4];
#pragma unroll
        for (int g = 0; g < 5; g++) {
            const float a = A[(size_t)j * NR + i0 + g];
            acc[g].x = fmaf(a, v.x, acc[g].x); acc[g].y = fmaf(a, v.y, acc[g].y);
            acc[g].z = fmaf(a, v.z, acc[g].z); acc[g].w = fmaf(a, v.w, acc[g].w);
        }
    }
#pragma unroll
    for (int g = 0; g < 5; g++) {
        const float4 p = ((const float4*)(inp + (size_t)(i0 + g) * TT))[t4];
        float4 r;
        r.x = p.x + acc[g].x; r.y = p.y + acc[g].y;
        r.z = p.z + acc[g].z; r.w = p.w + acc[g].w;
        ((float4*)(X + (size_t)(i0 + g) * TT))[t4] = r;
    }
}

// ---------------- persistent chain: whole 300-region sequence in ONE kernel ----------------
// grid = 240 blocks (1/CU resident; spin-safe). Block (rb,q) handles regions
// rb, rb+30, ..., rb+270.
// Critical-path sync = SENTINEL-IN-DATA: delta pre-filled 0xFFFFFFFF; readers
// sc1-poll their own 8 words directly (poll IS the data load, 1 IC RT).
// Flags (flagmat[300][32], lazily published post-vmcnt) only gate the BULK
// plain-float4 pipelined gather in the idle window; sentinel tail capped at 4.
__global__ __launch_bounds__(256, 1) void k_chain(
    const float* __restrict__ W,   const float* __restrict__ vb0,
    const float* __restrict__ va0, const float* __restrict__ A,
    const float* __restrict__ v_init, const float* __restrict__ X,
    const float* __restrict__ rbar0,  const float* __restrict__ ebar0,
    float* __restrict__ delta, int* __restrict__ flagmat,
    float* __restrict__ out_sp, float* __restrict__ outW,
    double* __restrict__ fpart) {

    const int tid  = threadIdx.x;
    const int lane = tid & 63;
    const int wv   = tid >> 6;
    const int rb   = blockIdx.x >> 3;
    const int qq   = blockIdx.x & 7;
    const int k_local = tid >> 2;        // 0..63
    const int mq   = tid & 3;            // m-quarter AND b-lane
    const int kg   = qq * 64 + k_local;  // global output column

    __shared__ __align__(16) float xs[4 * BSTR];
    __shared__ double ps[4];

    const float4* __restrict__ d4 = (const float4*)delta;

    for (int c = 0; c < NCH; c++) {
        const int i = rb + CH * c;
        // idle-window work: state scalars, W preload, X init, bulk gather
        const size_t base = (size_t)i * TT + (size_t)mq * NN + kg;
        const float vb0v = vb0[base];
        const float va0v = va0[base];
        const float vsi  = v_init[base];
        const float eb0v = ebar0[base];

        float w[128];
        const float* Wp = W + (((size_t)i * NN + (size_t)mq * 128) * NN) + kg;
#pragma unroll
        for (int s = 0; s < 128; s++) w[s] = Wp[(size_t)s * NN];

        // x accumulators: thread owns elements [4*tid,4*tid+4) and [4*tid+1024,+4)
        float4 r0 = ((const float4*)(X + (size_t)i * TT))[tid];
        float4 r1 = ((const float4*)(X + (size_t)i * TT))[tid + 256];

        int jdone = 0;
        if (i > 0) {
            // --- bulk: flag-gated plain pipelined float4 gather (idle window) ---
            for (;;) {
                int v = (lane < 32)
                    ? __hip_atomic_load(&flagmat[i * 32 + lane], __ATOMIC_RELAXED, __HIP_MEMORY_SCOPE_AGENT)
                    : 0x7fffffff;
                v = min(v, __shfl_xor(v, 1));
                v = min(v, __shfl_xor(v, 2));
                v = min(v, __shfl_xor(v, 4));
                v = min(v, __shfl_xor(v, 8));
                v = min(v, __shfl_xor(v, 16));
                int r = __shfl(v, 0);
                if (r > i) r = i;
                if (r > jdone) {
                    asm volatile("" ::: "memory");
                    for (int j = jdone; j < r; j++) {
                        const float a = A[(size_t)j * NR + i];
                        const float4 d0 = d4[j * 512 + tid];
                        const float4 d1 = d4[j * 512 + tid + 256];
                        r0.x = fmaf(a, d0.x, r0.x); r0.y = fmaf(a, d0.y, r0.y);
                        r0.z = fmaf(a, d0.z, r0.z); r0.w = fmaf(a, d0.w, r0.w);
                        r1.x = fmaf(a, d1.x, r1.x); r1.y = fmaf(a, d1.y, r1.y);
                        r1.z = fmaf(a, d1.z, r1.z); r1.w = fmaf(a, d1.w, r1.w);
                    }
                    jdone = r;
                }
                if (i - jdone <= 4) break;
            }
            // --- tail (<=4 regions): sentinel-poll own 8 words, critical path ---
            const int n = i - jdone;
            if (n > 0) {
                const int j0 = jdone;
                const int j1 = min(jdone + 1, i - 1);
                const int j2 = min(jdone + 2, i - 1);
                const int j3 = min(jdone + 3, i - 1);
                const float* p00 = delta + (size_t)j0 * TT + 4 * tid;
                const float* p10 = delta + (size_t)j1 * TT + 4 * tid;
                const float* p20 = delta + (size_t)j2 * TT + 4 * tid;
                const float* p30 = delta + (size_t)j3 * TT + 4 * tid;
                float4 a0, b0, a1, b1, a2, b2, a3, b3;
                ld8_sc_wait(p00, p00 + 1024, p10, p10 + 1024,
                            p20, p20 + 1024, p30, p30 + 1024,
                            a0, b0, a1, b1, a2, b2, a3, b3);
#define CONSUME(K, JK, AK, BK, PK)                                             \
                if (K < n) {                                                   \
                    while (!__all(ok8(AK, BK)))                                \
                        ld2_sc_wait(PK, PK + 1024, AK, BK);                    \
                    const float a_ = A[(size_t)JK * NR + i];                   \
                    r0.x = fmaf(a_, AK.x, r0.x); r0.y = fmaf(a_, AK.y, r0.y);  \
                    r0.z = fmaf(a_, AK.z, r0.z); r0.w = fmaf(a_, AK.w, r0.w);  \
                    r1.x = fmaf(a_, BK.x, r1.x); r1.y = fmaf(a_, BK.y, r1.y);  \
                    r1.z = fmaf(a_, BK.z, r1.z); r1.w = fmaf(a_, BK.w, r1.w);  \
                }
                CONSUME(0, j0, a0, b0, p00)
                CONSUME(1, j1, a1, b1, p10)
                CONSUME(2, j2, a2, b2, p20)
                CONSUME(3, j3, a3, b3, p30)
#undef CONSUME
            }
        }

        // --- publish x into LDS (float4-aligned in padded layout), one barrier ---
        {
            const int e0 = 4 * tid;          // elements e0..e0+3 (same quarter)
            const int e1 = 4 * tid + 1024;
            *(float4*)&xs[xidx(e0 >> 9, e0 & 511)] = r0;
            *(float4*)&xs[xidx(e1 >> 9, e1 & 511)] = r1;
        }
        __syncthreads();

        // --- GEMM: pred[b][kg] = sum_m x[b][m]*W[m][kg]; chains identical to R5 ---
        float acc0 = 0.f, acc1 = 0.f, acc2 = 0.f, acc3 = 0.f;
#pragma unroll
        for (int s4 = 0; s4 < 32; s4++) {
            const int mb = mq * QSTR + s4 * 4;
            float4 x0 = *(const float4*)&xs[mb];
            float4 x1 = *(const float4*)&xs[BSTR + mb];
            float4 x2 = *(const float4*)&xs[2 * BSTR + mb];
            float4 x3 = *(const float4*)&xs[3 * BSTR + mb];
            const float w0 = w[s4 * 4], w1 = w[s4 * 4 + 1], w2 = w[s4 * 4 + 2], w3 = w[s4 * 4 + 3];
            acc0 += x0.x * w0 + x0.y * w1 + x0.z * w2 + x0.w * w3;
            acc1 += x1.x * w0 + x1.y * w1 + x1.z * w2 + x1.w * w3;
            acc2 += x2.x * w0 + x2.y * w1 + x2.z * w2 + x2.w * w3;
            acc3 += x3.x * w0 + x3.y * w1 + x3.z * w2 + x3.w * w3;
        }
        acc0 += __shfl_xor(acc0, 1); acc0 += __shfl_xor(acc0, 2);
        acc1 += __shfl_xor(acc1, 1); acc1 += __shfl_xor(acc1, 2);
        acc2 += __shfl_xor(acc2, 1); acc2 += __shfl_xor(acc2, 2);
        acc3 += __shfl_xor(acc3, 1); acc3 += __shfl_xor(acc3, 2);
        const float pred = (mq == 0) ? acc0 : (mq == 1) ? acc1 : (mq == 2) ? acc2 : acc3;

        // --- state update for (b=mq, n=kg); delta sc1 store FIRST (the signal) ---
        const float vb  = TAU * vb0v + OMT * pred;
        const float va  = TAU * va0v;
        const float vs  = TAU * vsi + OMT * (vb - va);
        __hip_atomic_store(&delta[base], vs - vsi, __ATOMIC_RELAXED, __HIP_MEMORY_SCOPE_AGENT);
        const float mis = vs - vb;

        // --- lazy flag publish (bulk-path hint only; off reader critical path) ---
        asm volatile("s_waitcnt vmcnt(0)" ::: "memory");   // delta in IC before flag
        {
            const int slot = (qq << 2) + wv;
            for (int r = i + 1 + lane; r < NR; r += 64)
                __hip_atomic_store(&flagmat[r * 32 + slot], i + 1,
                                   __ATOMIC_RELAXED, __HIP_MEMORY_SCOPE_AGENT);
        }
        out_sp[base] = (vs > 0.f) ? 1.f : 0.f;
        __syncthreads();   // protect xs: all GEMM reads done before rbar overwrite

        // --- fused Hebbian (off critical path): rbar in-place into xs, float4 ---
#pragma unroll
        for (int s = 0; s < 2; s++) {
            const int e = 4 * tid + s * 1024;
            float* xp = &xs[xidx(e >> 9, e & 511)];
            const float4 rr = ((const float4*)(rbar0 + (size_t)i * TT))[tid + s * 256];
            float4 xv = *(float4*)xp;
            xv.x = OMA * rr.x + ALPH * xv.x; xv.y = OMA * rr.y + ALPH * xv.y;
            xv.z = OMA * rr.z + ALPH * xv.z; xv.w = OMA * rr.w + ALPH * xv.w;
            *(float4*)xp = xv;
        }
        __syncthreads();

        const float e_own = OMA * eb0v + ALPH * mis;
        const int qb = lane & ~3;
        const float e0 = __shfl(e_own, qb + 0);
        const float e1 = __shfl(e_own, qb + 1);
        const float e2 = __shfl(e_own, qb + 2);
        const float e3 = __shfl(e_own, qb + 3);

#pragma unroll
        for (int s = 0; s < 128; s++) {
            const int m = mq * 128 + s;
            const int xo = mq * QSTR + s;
            const float dw = e0 * xs[xo] + e1 * xs[BSTR + xo] + e2 * xs[2 * BSTR + xo] + e3 * xs[3 * BSTR + xo];
            outW[(((size_t)i * NN + m) * NN) + kg] = w[s] + LRQ * dw;
        }

        // --- F partial (deterministic per-block double) ---
        double p = (double)mis * (double)mis;
#pragma unroll
        for (int off = 32; off; off >>= 1) p += __shfl_xor(p, off);
        if (lane == 0) ps[wv] = p;
        __syncthreads();
        if (tid == 0) fpart[(size_t)i * SLC + qq] = ps[0] + ps[1] + ps[2] + ps[3];
        __syncthreads();   // ps consumed before next iteration rewrites it
    }
}

// ---------------- final F reduction ----------------
__global__ __launch_bounds__(256) void k_fin(const double* __restrict__ fpart,
                                             float* __restrict__ outF) {
    __shared__ double ps[256];
    double s = 0.0;
    for (int idx = threadIdx.x; idx < NR * SLC; idx += 256) s += fpart[idx];
    ps[threadIdx.x] = s;
    __syncthreads();
    for (int st = 128; st; st >>= 1) {
        if (threadIdx.x < st) ps[threadIdx.x] += ps[threadIdx.x + st];
        __syncthreads();
    }
    if (threadIdx.x == 0) outF[0] = (float)(ps[0] / 614400.0);
}

extern "C" void kernel_launch(void* const* d_in, const int* in_sizes, int n_in,
                              void* d_out, int out_size, void* d_ws, size_t ws_size,
                              hipStream_t stream) {
    const float* v_s0  = (const float*)d_in[0];
    const float* v_b0  = (const float*)d_in[1];
    const float* v_a0  = (const float*)d_in[2];
    const float* rbar0 = (const float*)d_in[3];
    const float* ebar0 = (const float*)d_in[4];
    const float* W     = (const float*)d_in[5];
    const float* A     = (const float*)d_in[6];
    const float* inp   = (const float*)d_in[7];
    const float* noise = (const float*)d_in[8];

    float* out_sp = (float*)d_out;                 // [300,4,512]
    float* out_W  = out_sp + 614400;               // [300,512,512]
    float* out_F  = out_sp + 79257600;             // scalar

    char* ws = (char*)d_ws;
    float* v_init  = (float*)ws;                       // 614400 f
    float* X       = v_init + 614400;                  // 614400 f
    float* delta   = X + 614400;                       // 614400 f @ byte 4915200
    int*   flagmat = (int*)(ws + 7372800);             // 300 rows x 32 ints (128B rows)
    double* fpart  = (double*)(ws + 7411200);          // 2400 doubles

    // one memset covers delta sentinel (0xFFFFFFFF = NaN) AND flagmat (-1;
    // min-reduce semantics identical to 0-init since published values are >=1)
    hipMemsetAsync(delta, 0xFF, 2457600 + NR * 32 * sizeof(int), stream);
    k_init<<<600, 256, 0, stream>>>(v_s0, noise, v_init);
    k_base<<<120, 256, 0, stream>>>(A, v_init, inp, X);
    k_chain<<<CH * SLC, 256, 0, stream>>>(W, v_b0, v_a0, A, v_init, X,
                                          rbar0, ebar0, delta, flagmat,
                                          out_sp, out_W, fpart);
    k_fin<<<1, 256, 0, stream>>>(fpart, out_F);
}

// Round 9
// 1281.607 us; speedup vs baseline: 2.5714x; 1.0237x over previous
//
#include <hip/hip_runtime.h>

// Problem constants
#define NR   300
#define NB   4
#define NN   512
#define TT   2048          // NB*NN
#define CH   30            // region-row stride (persistent blocks)
#define NCH  10            // regions per block
#define SLC  8             // k-slice blocks per region (64 k each)

#define TAU   0.8f
#define OMT   0.2f         // 1-TAU
#define ALPH  0.05f
#define OMA   0.95f
#define LRQ   5.0e-6f      // HEBB_LR / B = 2e-5/4
#define NSC   0.02f

#define SENT  0xFFFFFFFFu  // delta sentinel (negative qNaN pattern; vs-vsi is always finite)

// padded LDS x layout: [b][quarter][128] with quarter stride 136 floats
#define QSTR 136
#define BSTR 544           // 4*136
__device__ __forceinline__ int xidx(int b, int n) {
    return b * BSTR + (n >> 7) * QSTR + (n & 127);
}

// ---- sc0/sc1 (IC-coherent) 16B loads; load+wait fused in ONE asm block so
// outputs are fully defined at asm end (no spill-before-wait hazard: R8 lesson).
__device__ __forceinline__ void ld2_sc_wait(const float* p0, const float* p1,
                                            float4& a, float4& b) {
    asm volatile(
        "global_load_dwordx4 %0, %2, off sc0 sc1\n\t"
        "global_load_dwordx4 %1, %3, off sc0 sc1\n\t"
        "s_waitcnt vmcnt(0)"
        : "=&v"(a), "=&v"(b)
        : "v"(p0), "v"(p1)
        : "memory");
}

__device__ __forceinline__ void ld8_sc_wait(
        const float* p00, const float* p01, const float* p10, const float* p11,
        const float* p20, const float* p21, const float* p30, const float* p31,
        float4& a0, float4& b0, float4& a1, float4& b1,
        float4& a2, float4& b2, float4& a3, float4& b3) {
    asm volatile(
        "global_load_dwordx4 %0, %8, off sc0 sc1\n\t"
        "global_load_dwordx4 %1, %9, off sc0 sc1\n\t"
        "global_load_dwordx4 %2, %10, off sc0 sc1\n\t"
        "global_load_dwordx4 %3, %11, off sc0 sc1\n\t"
        "global_load_dwordx4 %4, %12, off sc0 sc1\n\t"
        "global_load_dwordx4 %5, %13, off sc0 sc1\n\t"
        "global_load_dwordx4 %6, %14, off sc0 sc1\n\t"
        "global_load_dwordx4 %7, %15, off sc0 sc1\n\t"
        "s_waitcnt vmcnt(0)"
        : "=&v"(a0), "=&v"(b0), "=&v"(a1), "=&v"(b1),
          "=&v"(a2), "=&v"(b2), "=&v"(a3), "=&v"(b3)
        : "v"(p00), "v"(p01), "v"(p10), "v"(p11),
          "v"(p20), "v"(p21), "v"(p30), "v"(p31)
        : "memory");
}

__device__ __forceinline__ bool ok8(const float4& a, const float4& b) {
    return __float_as_uint(a.x) != SENT && __float_as_uint(a.y) != SENT &&
           __float_as_uint(a.z) != SENT && __float_as_uint(a.w) != SENT &&
           __float_as_uint(b.x) != SENT && __float_as_uint(b.y) != SENT &&
           __float_as_uint(b.z) != SENT && __float_as_uint(b.w) != SENT;
}

// ---------------- v_init = v_s0 + 0.02*noise ----------------
__global__ __launch_bounds__(256) void k_init(const float* __restrict__ vs0,
                                              const float* __restrict__ noise,
                                              float* __restrict__ v_init) {
    int idx = blockIdx.x * 256 + threadIdx.x;           // float4 index
    const float4* a = (const float4*)vs0;
    const float4* b = (const float4*)noise;
    float4* o = (float4*)v_init;
    float4 va = a[idx], vb = b[idx];
    float4 r;
    r.x = va.x + NSC * vb.x; r.y = va.y + NSC * vb.y;
    r.z = va.z + NSC * vb.z; r.w = va.w + NSC * vb.w;
    o[idx] = r;
}

// ---------------- X[i,t] = inp[i,t] + sum_j A[j,i]*v_init[j,t] ----------------
__global__ __launch_bounds__(256) void k_base(const float* __restrict__ A,
                                              const float* __restrict__ v_init,
                                              const float* __restrict__ inp,
                                              float* __restrict__ X) {
    const int i0 = (blockIdx.x >> 1) * 5;
    const int t4 = (blockIdx.x & 1) * 256 + threadIdx.x;   // float4 index 0..511
    float4 acc[5];
#pragma unroll
    for (int g = 0; g < 5; g++) acc[g] = make_float4(0.f, 0.f, 0.f, 0.f);
    for (int j = 0; j < NR; j++) {
        const float4 v = ((const float4*)(v_init + (size_t)j * TT))[t4];
#pragma unroll
        for (int g = 0; g < 5; g++) {
            const float a = A[(size_t)j * NR + i0 + g];
            acc[g].x = fmaf(a, v.x, acc[g].x); acc[g].y = fmaf(a, v.y, acc[g].y);
            acc[g].z = fmaf(a, v.z, acc[g].z); acc[g].w = fmaf(a, v.w, acc[g].w);
        }
    }
#pragma unroll
    for (int g = 0; g < 5; g++) {
        const float4 p = ((const float4*)(inp + (size_t)(i0 + g) * TT))[t4];
        float4 r;
        r.x = p.x + acc[g].x; r.y = p.y + acc[g].y;
        r.z = p.z + acc[g].z; r.w = p.w + acc[g].w;
        ((float4*)(X + (size_t)(i0 + g) * TT))[t4] = r;
    }
}

// ---------------- persistent chain: whole 300-region sequence in ONE kernel ----------------
// grid = 240 blocks (1/CU resident; spin-safe). Block (rb,q) handles regions
// rb, rb+30, ..., rb+270.
// Critical-path sync = SENTINEL-IN-DATA (R6-proven fused load+wait polling).
// Bulk gather (flag-gated plain float4 loads) runs in the idle window with
// tiered s_sleep backoff so ~230 idle blocks don't flood the IC with polls.
__global__ __launch_bounds__(256, 1) void k_chain(
    const float* __restrict__ W,   const float* __restrict__ vb0,
    const float* __restrict__ va0, const float* __restrict__ A,
    const float* __restrict__ v_init, const float* __restrict__ X,
    const float* __restrict__ rbar0,  const float* __restrict__ ebar0,
    float* __restrict__ delta, int* __restrict__ flagmat,
    float* __restrict__ out_sp, float* __restrict__ outW,
    double* __restrict__ fpart) {

    const int tid  = threadIdx.x;
    const int lane = tid & 63;
    const int wv   = tid >> 6;
    const int rb   = blockIdx.x >> 3;
    const int qq   = blockIdx.x & 7;
    const int k_local = tid >> 2;        // 0..63
    const int mq   = tid & 3;            // m-quarter AND b-lane
    const int kg   = qq * 64 + k_local;  // global output column

    __shared__ __align__(16) float xs[4 * BSTR];
    __shared__ double ps[4];

    const float4* __restrict__ d4 = (const float4*)delta;

    for (int c = 0; c < NCH; c++) {
        const int i = rb + CH * c;
        // idle-window work: state scalars, W preload, X init, bulk gather
        const size_t base = (size_t)i * TT + (size_t)mq * NN + kg;
        const float vb0v = vb0[base];
        const float va0v = va0[base];
        const float vsi  = v_init[base];
        const float eb0v = ebar0[base];

        float w[128];
        const float* Wp = W + (((size_t)i * NN + (size_t)mq * 128) * NN) + kg;
#pragma unroll
        for (int s = 0; s < 128; s++) w[s] = Wp[(size_t)s * NN];

        // x accumulators: thread owns elements [4*tid,4*tid+4) and [4*tid+1024,+4)
        float4 r0 = ((const float4*)(X + (size_t)i * TT))[tid];
        float4 r1 = ((const float4*)(X + (size_t)i * TT))[tid + 256];

        int jdone = 0;
        if (i > 0) {
            // --- bulk: flag-gated plain pipelined float4 gather, with tiered backoff ---
            for (;;) {
                int v = (lane < 32)
                    ? __hip_atomic_load(&flagmat[i * 32 + lane], __ATOMIC_RELAXED, __HIP_MEMORY_SCOPE_AGENT)
                    : 0x7fffffff;
                v = min(v, __shfl_xor(v, 1));
                v = min(v, __shfl_xor(v, 2));
                v = min(v, __shfl_xor(v, 4));
                v = min(v, __shfl_xor(v, 8));
                v = min(v, __shfl_xor(v, 16));
                int r = __shfl(v, 0);
                if (r > i) r = i;
                const bool prog = (r > jdone);
                if (prog) {
                    asm volatile("" ::: "memory");
                    for (int j = jdone; j < r; j++) {
                        const float a = A[(size_t)j * NR + i];
                        const float4 d0 = d4[j * 512 + tid];
                        const float4 d1 = d4[j * 512 + tid + 256];
                        r0.x = fmaf(a, d0.x, r0.x); r0.y = fmaf(a, d0.y, r0.y);
                        r0.z = fmaf(a, d0.z, r0.z); r0.w = fmaf(a, d0.w, r0.w);
                        r1.x = fmaf(a, d1.x, r1.x); r1.y = fmaf(a, d1.y, r1.y);
                        r1.z = fmaf(a, d1.z, r1.z); r1.w = fmaf(a, d1.w, r1.w);
                    }
                    jdone = r;
                }
                const int dist = i - jdone;
                if (dist <= 4) break;
                if (!prog) {                 // no progress: back off by distance
                    if (dist > 24)      __builtin_amdgcn_s_sleep(32);
                    else if (dist > 10) __builtin_amdgcn_s_sleep(8);
                    else                __builtin_amdgcn_s_sleep(1);
                }
            }
            // --- tail (<=4 regions): sentinel-poll own 8 words (fused load+wait) ---
            const int n = i - jdone;
            if (n > 0) {
                const int j0 = jdone;
                const int j1 = min(jdone + 1, i - 1);
                const int j2 = min(jdone + 2, i - 1);
                const int j3 = min(jdone + 3, i - 1);
                const float* p00 = delta + (size_t)j0 * TT + 4 * tid;
                const float* p10 = delta + (size_t)j1 * TT + 4 * tid;
                const float* p20 = delta + (size_t)j2 * TT + 4 * tid;
                const float* p30 = delta + (size_t)j3 * TT + 4 * tid;
                float4 a0, b0, a1, b1, a2, b2, a3, b3;
                ld8_sc_wait(p00, p00 + 1024, p10, p10 + 1024,
                            p20, p20 + 1024, p30, p30 + 1024,
                            a0, b0, a1, b1, a2, b2, a3, b3);
#define CONSUME(K, JK, AK, BK, PK)                                             \
                if (K < n) {                                                   \
                    while (!__all(ok8(AK, BK)))                                \
                        ld2_sc_wait(PK, PK + 1024, AK, BK);                    \
                    const float a_ = A[(size_t)JK * NR + i];                   \
                    r0.x = fmaf(a_, AK.x, r0.x); r0.y = fmaf(a_, AK.y, r0.y);  \
                    r0.z = fmaf(a_, AK.z, r0.z); r0.w = fmaf(a_, AK.w, r0.w);  \
                    r1.x = fmaf(a_, BK.x, r1.x); r1.y = fmaf(a_, BK.y, r1.y);  \
                    r1.z = fmaf(a_, BK.z, r1.z); r1.w = fmaf(a_, BK.w, r1.w);  \
                }
                CONSUME(0, j0, a0, b0, p00)
                CONSUME(1, j1, a1, b1, p10)
                CONSUME(2, j2, a2, b2, p20)
                CONSUME(3, j3, a3, b3, p30)
#undef CONSUME
            }
        }

        // --- publish x into LDS (float4-aligned in padded layout), one barrier ---
        {
            const int e0 = 4 * tid;          // elements e0..e0+3 (same quarter)
            const int e1 = 4 * tid + 1024;
            *(float4*)&xs[xidx(e0 >> 9, e0 & 511)] = r0;
            *(float4*)&xs[xidx(e1 >> 9, e1 & 511)] = r1;
        }
        __syncthreads();

        // --- GEMM: pred[b][kg] = sum_m x[b][m]*W[m][kg]; chains identical to R6 ---
        float acc0 = 0.f, acc1 = 0.f, acc2 = 0.f, acc3 = 0.f;
#pragma unroll
        for (int s4 = 0; s4 < 32; s4++) {
            const int mb = mq * QSTR + s4 * 4;
            float4 x0 = *(const float4*)&xs[mb];
            float4 x1 = *(const float4*)&xs[BSTR + mb];
            float4 x2 = *(const float4*)&xs[2 * BSTR + mb];
            float4 x3 = *(const float4*)&xs[3 * BSTR + mb];
            const float w0 = w[s4 * 4], w1 = w[s4 * 4 + 1], w2 = w[s4 * 4 + 2], w3 = w[s4 * 4 + 3];
            acc0 += x0.x * w0 + x0.y * w1 + x0.z * w2 + x0.w * w3;
            acc1 += x1.x * w0 + x1.y * w1 + x1.z * w2 + x1.w * w3;
            acc2 += x2.x * w0 + x2.y * w1 + x2.z * w2 + x2.w * w3;
            acc3 += x3.x * w0 + x3.y * w1 + x3.z * w2 + x3.w * w3;
        }
        acc0 += __shfl_xor(acc0, 1); acc0 += __shfl_xor(acc0, 2);
        acc1 += __shfl_xor(acc1, 1); acc1 += __shfl_xor(acc1, 2);
        acc2 += __shfl_xor(acc2, 1); acc2 += __shfl_xor(acc2, 2);
        acc3 += __shfl_xor(acc3, 1); acc3 += __shfl_xor(acc3, 2);
        const float pred = (mq == 0) ? acc0 : (mq == 1) ? acc1 : (mq == 2) ? acc2 : acc3;

        // --- state update for (b=mq, n=kg); delta sc1 store FIRST (the signal) ---
        const float vb  = TAU * vb0v + OMT * pred;
        const float va  = TAU * va0v;
        const float vs  = TAU * vsi + OMT * (vb - va);
        __hip_atomic_store(&delta[base], vs - vsi, __ATOMIC_RELAXED, __HIP_MEMORY_SCOPE_AGENT);
        const float mis = vs - vb;

        // --- lazy flag publish (bulk-path hint only; off reader critical path) ---
        asm volatile("s_waitcnt vmcnt(0)" ::: "memory");   // delta in IC before flag
        {
            const int slot = (qq << 2) + wv;
            for (int r = i + 1 + lane; r < NR; r += 64)
                __hip_atomic_store(&flagmat[r * 32 + slot], i + 1,
                                   __ATOMIC_RELAXED, __HIP_MEMORY_SCOPE_AGENT);
        }
        out_sp[base] = (vs > 0.f) ? 1.f : 0.f;
        __syncthreads();   // protect xs: all GEMM reads done before rbar overwrite

        // --- fused Hebbian (off critical path): rbar in-place into xs, float4 ---
#pragma unroll
        for (int s = 0; s < 2; s++) {
            const int e = 4 * tid + s * 1024;
            float* xp = &xs[xidx(e >> 9, e & 511)];
            const float4 rr = ((const float4*)(rbar0 + (size_t)i * TT))[tid + s * 256];
            float4 xv = *(float4*)xp;
            xv.x = OMA * rr.x + ALPH * xv.x; xv.y = OMA * rr.y + ALPH * xv.y;
            xv.z = OMA * rr.z + ALPH * xv.z; xv.w = OMA * rr.w + ALPH * xv.w;
            *(float4*)xp = xv;
        }
        __syncthreads();

        const float e_own = OMA * eb0v + ALPH * mis;
        const int qb = lane & ~3;
        const float e0 = __shfl(e_own, qb + 0);
        const float e1 = __shfl(e_own, qb + 1);
        const float e2 = __shfl(e_own, qb + 2);
        const float e3 = __shfl(e_own, qb + 3);

#pragma unroll
        for (int s = 0; s < 128; s++) {
            const int m = mq * 128 + s;
            const int xo = mq * QSTR + s;
            const float dw = e0 * xs[xo] + e1 * xs[BSTR + xo] + e2 * xs[2 * BSTR + xo] + e3 * xs[3 * BSTR + xo];
            outW[(((size_t)i * NN + m) * NN) + kg] = w[s] + LRQ * dw;
        }

        // --- F partial (deterministic per-block double) ---
        double p = (double)mis * (double)mis;
#pragma unroll
        for (int off = 32; off; off >>= 1) p += __shfl_xor(p, off);
        if (lane == 0) ps[wv] = p;
        __syncthreads();
        if (tid == 0) fpart[(size_t)i * SLC + qq] = ps[0] + ps[1] + ps[2] + ps[3];
        __syncthreads();   // ps consumed before next iteration rewrites it
    }
}

// ---------------- final F reduction ----------------
__global__ __launch_bounds__(256) void k_fin(const double* __restrict__ fpart,
                                             float* __restrict__ outF) {
    __shared__ double ps[256];
    double s = 0.0;
    for (int idx = threadIdx.x; idx < NR * SLC; idx += 256) s += fpart[idx];
    ps[threadIdx.x] = s;
    __syncthreads();
    for (int st = 128; st; st >>= 1) {
        if (threadIdx.x < st) ps[threadIdx.x] += ps[threadIdx.x + st];
        __syncthreads();
    }
    if (threadIdx.x == 0) outF[0] = (float)(ps[0] / 614400.0);
}

extern "C" void kernel_launch(void* const* d_in, const int* in_sizes, int n_in,
                              void* d_out, int out_size, void* d_ws, size_t ws_size,
                              hipStream_t stream) {
    const float* v_s0  = (const float*)d_in[0];
    const float* v_b0  = (const float*)d_in[1];
    const float* v_a0  = (const float*)d_in[2];
    const float* rbar0 = (const float*)d_in[3];
    const float* ebar0 = (const float*)d_in[4];
    const float* W     = (const float*)d_in[5];
    const float* A     = (const float*)d_in[6];
    const float* inp   = (const float*)d_in[7];
    const float* noise = (const float*)d_in[8];

    float* out_sp = (float*)d_out;                 // [300,4,512]
    float* out_W  = out_sp + 614400;               // [300,512,512]
    float* out_F  = out_sp + 79257600;             // scalar

    char* ws = (char*)d_ws;
    float* v_init  = (float*)ws;                       // 614400 f
    float* X       = v_init + 614400;                  // 614400 f
    float* delta   = X + 614400;                       // 614400 f @ byte 4915200
    int*   flagmat = (int*)(ws + 7372800);             // 300 rows x 32 ints (128B rows)
    double* fpart  = (double*)(ws + 7411200);          // 2400 doubles

    // one memset covers delta sentinel (0xFFFFFFFF = NaN) AND flagmat (-1;
    // min-reduce semantics identical since published values are >= 1)
    (void)hipMemsetAsync(delta, 0xFF, 2457600 + NR * 32 * sizeof(int), stream);
    k_init<<<600, 256, 0, stream>>>(v_s0, noise, v_init);
    k_base<<<120, 256, 0, stream>>>(A, v_init, inp, X);
    k_chain<<<CH * SLC, 256, 0, stream>>>(W, v_b0, v_a0, A, v_init, X,
                                          rbar0, ebar0, delta, flagmat,
                                          out_sp, out_W, fpart);
    k_fin<<<1, 256, 0, stream>>>(fpart, out_F);
}

// Round 10
// 1251.558 us; speedup vs baseline: 2.6331x; 1.0240x over previous
//
#include <hip/hip_runtime.h>

// Problem constants
#define NR   300
#define NB   4
#define NN   512
#define TT   2048          // NB*NN
#define CH   30            // region-row stride (persistent blocks)
#define NCH  10            // regions per block
#define SLC  8             // k-slice blocks per region (64 k each)

#define TAU   0.8f
#define OMT   0.2f         // 1-TAU
#define ALPH  0.05f
#define OMA   0.95f
#define LRQ   5.0e-6f      // HEBB_LR / B = 2e-5/4
#define NSC   0.02f

#define SENT  0xFFFFFFFFu  // delta sentinel (negative qNaN; vs-vsi always finite)

// padded LDS x layout: [b][quarter][128] with quarter stride 136 floats
#define QSTR 136
#define BSTR 544           // 4*136
__device__ __forceinline__ int xidx(int b, int n) {
    return b * BSTR + (n >> 7) * QSTR + (n & 127);
}

// ---- TWO-STREAM sentinel poll, fully self-contained in one asm block.
// Stream buffers are hard-clobbered v[48:63] (never C++-visible -> no
// spill-before-wait hazard, R8 lesson). Streams staggered ~RT/2 by s_sleep.
// Loop invariant: after each reissue the queue is 4 deep, so vmcnt(2) always
// certifies the stream being checked. Exit paths drain vmcnt(0) so pending
// writes to clobbered regs can't corrupt later code.
__device__ __forceinline__ void poll8_2s(const float* p0, const float* p1,
                                         float& o0, float& o1, float& o2, float& o3,
                                         float& o4, float& o5, float& o6, float& o7) {
    unsigned long long sacc;
    asm volatile(
        "global_load_dwordx4 v[48:51], %9, off sc0 sc1\n\t"
        "global_load_dwordx4 v[52:55], %10, off sc0 sc1\n\t"
        "s_sleep 5\n\t"
        "global_load_dwordx4 v[56:59], %9, off sc0 sc1\n\t"
        "global_load_dwordx4 v[60:63], %10, off sc0 sc1\n\t"
        "Lpoll_%=:\n\t"
        "s_waitcnt vmcnt(2)\n\t"
        "v_cmp_ne_u32 vcc, -1, v48\n\t"
        "s_mov_b64 %8, vcc\n\t"
        "v_cmp_ne_u32 vcc, -1, v49\n\t"
        "s_and_b64 %8, %8, vcc\n\t"
        "v_cmp_ne_u32 vcc, -1, v50\n\t"
        "s_and_b64 %8, %8, vcc\n\t"
        "v_cmp_ne_u32 vcc, -1, v51\n\t"
        "s_and_b64 %8, %8, vcc\n\t"
        "v_cmp_ne_u32 vcc, -1, v52\n\t"
        "s_and_b64 %8, %8, vcc\n\t"
        "v_cmp_ne_u32 vcc, -1, v53\n\t"
        "s_and_b64 %8, %8, vcc\n\t"
        "v_cmp_ne_u32 vcc, -1, v54\n\t"
        "s_and_b64 %8, %8, vcc\n\t"
        "v_cmp_ne_u32 vcc, -1, v55\n\t"
        "s_and_b64 %8, %8, vcc\n\t"
        "s_cmp_eq_u64 %8, exec\n\t"
        "s_cbranch_scc1 Ldone0_%=\n\t"
        "global_load_dwordx4 v[48:51], %9, off sc0 sc1\n\t"
        "global_load_dwordx4 v[52:55], %10, off sc0 sc1\n\t"
        "s_waitcnt vmcnt(2)\n\t"
        "v_cmp_ne_u32 vcc, -1, v56\n\t"
        "s_mov_b64 %8, vcc\n\t"
        "v_cmp_ne_u32 vcc, -1, v57\n\t"
        "s_and_b64 %8, %8, vcc\n\t"
        "v_cmp_ne_u32 vcc, -1, v58\n\t"
        "s_and_b64 %8, %8, vcc\n\t"
        "v_cmp_ne_u32 vcc, -1, v59\n\t"
        "s_and_b64 %8, %8, vcc\n\t"
        "v_cmp_ne_u32 vcc, -1, v60\n\t"
        "s_and_b64 %8, %8, vcc\n\t"
        "v_cmp_ne_u32 vcc, -1, v61\n\t"
        "s_and_b64 %8, %8, vcc\n\t"
        "v_cmp_ne_u32 vcc, -1, v62\n\t"
        "s_and_b64 %8, %8, vcc\n\t"
        "v_cmp_ne_u32 vcc, -1, v63\n\t"
        "s_and_b64 %8, %8, vcc\n\t"
        "s_cmp_eq_u64 %8, exec\n\t"
        "s_cbranch_scc1 Ldone1_%=\n\t"
        "global_load_dwordx4 v[56:59], %9, off sc0 sc1\n\t"
        "global_load_dwordx4 v[60:63], %10, off sc0 sc1\n\t"
        "s_branch Lpoll_%=\n\t"
        "Ldone1_%=:\n\t"
        "s_waitcnt vmcnt(0)\n\t"
        "v_mov_b32 v48, v56\n\t"
        "v_mov_b32 v49, v57\n\t"
        "v_mov_b32 v50, v58\n\t"
        "v_mov_b32 v51, v59\n\t"
        "v_mov_b32 v52, v60\n\t"
        "v_mov_b32 v53, v61\n\t"
        "v_mov_b32 v54, v62\n\t"
        "v_mov_b32 v55, v63\n\t"
        "Ldone0_%=:\n\t"
        "s_waitcnt vmcnt(0)\n\t"
        "v_mov_b32 %0, v48\n\t"
        "v_mov_b32 %1, v49\n\t"
        "v_mov_b32 %2, v50\n\t"
        "v_mov_b32 %3, v51\n\t"
        "v_mov_b32 %4, v52\n\t"
        "v_mov_b32 %5, v53\n\t"
        "v_mov_b32 %6, v54\n\t"
        "v_mov_b32 %7, v55"
        : "=v"(o0), "=v"(o1), "=v"(o2), "=v"(o3),
          "=v"(o4), "=v"(o5), "=v"(o6), "=v"(o7), "=&s"(sacc)
        : "v"(p0), "v"(p1)
        : "vcc", "memory",
          "v48","v49","v50","v51","v52","v53","v54","v55",
          "v56","v57","v58","v59","v60","v61","v62","v63");
}

// ---------------- v_init = v_s0 + 0.02*noise ----------------
__global__ __launch_bounds__(256) void k_init(const float* __restrict__ vs0,
                                              const float* __restrict__ noise,
                                              float* __restrict__ v_init) {
    int idx = blockIdx.x * 256 + threadIdx.x;           // float4 index
    const float4* a = (const float4*)vs0;
    const float4* b = (const float4*)noise;
    float4* o = (float4*)v_init;
    float4 va = a[idx], vb = b[idx];
    float4 r;
    r.x = va.x + NSC * vb.x; r.y = va.y + NSC * vb.y;
    r.z = va.z + NSC * vb.z; r.w = va.w + NSC * vb.w;
    o[idx] = r;
}

// ---------------- X[i,t] = inp[i,t] + sum_j A[j,i]*v_init[j,t] ----------------
__global__ __launch_bounds__(256) void k_base(const float* __restrict__ A,
                                              const float* __restrict__ v_init,
                                              const float* __restrict__ inp,
                                              float* __restrict__ X) {
    const int i0 = (blockIdx.x >> 1) * 5;
    const int t4 = (blockIdx.x & 1) * 256 + threadIdx.x;   // float4 index 0..511
    float4 acc[5];
#pragma unroll
    for (int g = 0; g < 5; g++) acc[g] = make_float4(0.f, 0.f, 0.f, 0.f);
    for (int j = 0; j < NR; j++) {
        const float4 v = ((const float4*)(v_init + (size_t)j * TT))[t4];
#pragma unroll
        for (int g = 0; g < 5; g++) {
            const float a = A[(size_t)j * NR + i0 + g];
            acc[g].x = fmaf(a, v.x, acc[g].x); acc[g].y = fmaf(a, v.y, acc[g].y);
            acc[g].z = fmaf(a, v.z, acc[g].z); acc[g].w = fmaf(a, v.w, acc[g].w);
        }
    }
#pragma unroll
    for (int g = 0; g < 5; g++) {
        const float4 p = ((const float4*)(inp + (size_t)(i0 + g) * TT))[t4];
        float4 r;
        r.x = p.x + acc[g].x; r.y = p.y + acc[g].y;
        r.z = p.z + acc[g].z; r.w = p.w + acc[g].w;
        ((float4*)(X + (size_t)(i0 + g) * TT))[t4] = r;
    }
}

// ---------------- persistent chain: whole 300-region sequence in ONE kernel ----------------
__global__ __launch_bounds__(256, 1) void k_chain(
    const float* __restrict__ W,   const float* __restrict__ vb0,
    const float* __restrict__ va0, const float* __restrict__ A,
    const float* __restrict__ v_init, const float* __restrict__ X,
    const float* __restrict__ rbar0,  const float* __restrict__ ebar0,
    float* __restrict__ delta, int* __restrict__ flagmat,
    float* __restrict__ out_sp, float* __restrict__ outW,
    double* __restrict__ fpart) {

    const int tid  = threadIdx.x;
    const int lane = tid & 63;
    const int wv   = tid >> 6;
    const int rb   = blockIdx.x >> 3;
    const int qq   = blockIdx.x & 7;
    const int k_local = tid >> 2;        // 0..63
    const int mq   = tid & 3;            // m-quarter AND b-lane
    const int kg   = qq * 64 + k_local;  // global output column

    __shared__ __align__(16) float xs[4 * BSTR];
    __shared__ double ps[4];

    const float4* __restrict__ d4 = (const float4*)delta;

    for (int c = 0; c < NCH; c++) {
        const int i = rb + CH * c;
        const size_t base = (size_t)i * TT + (size_t)mq * NN + kg;
        const float vb0v = vb0[base];
        const float va0v = va0[base];
        const float vsi  = v_init[base];
        const float eb0v = ebar0[base];

        // W preload with nontemporal hint (stream, no L2 pollution)
        float w[128];
        const float* Wp = W + (((size_t)i * NN + (size_t)mq * 128) * NN) + kg;
#pragma unroll
        for (int s = 0; s < 128; s++) w[s] = __builtin_nontemporal_load(&Wp[(size_t)s * NN]);

        float4 r0 = ((const float4*)(X + (size_t)i * TT))[tid];
        float4 r1 = ((const float4*)(X + (size_t)i * TT))[tid + 256];

        int jdone = 0;
        if (i > 0) {
            // --- bulk: flag-gated plain pipelined float4 gather, tiered backoff ---
            for (;;) {
                int v = (lane < 32)
                    ? __hip_atomic_load(&flagmat[i * 32 + lane], __ATOMIC_RELAXED, __HIP_MEMORY_SCOPE_AGENT)
                    : 0x7fffffff;
                v = min(v, __shfl_xor(v, 1));
                v = min(v, __shfl_xor(v, 2));
                v = min(v, __shfl_xor(v, 4));
                v = min(v, __shfl_xor(v, 8));
                v = min(v, __shfl_xor(v, 16));
                int r = __shfl(v, 0);
                if (r > i) r = i;
                const bool prog = (r > jdone);
                if (prog) {
                    asm volatile("" ::: "memory");
                    for (int j = jdone; j < r; j++) {
                        const float a = A[(size_t)j * NR + i];
                        const float4 d0 = d4[j * 512 + tid];
                        const float4 d1 = d4[j * 512 + tid + 256];
                        r0.x = fmaf(a, d0.x, r0.x); r0.y = fmaf(a, d0.y, r0.y);
                        r0.z = fmaf(a, d0.z, r0.z); r0.w = fmaf(a, d0.w, r0.w);
                        r1.x = fmaf(a, d1.x, r1.x); r1.y = fmaf(a, d1.y, r1.y);
                        r1.z = fmaf(a, d1.z, r1.z); r1.w = fmaf(a, d1.w, r1.w);
                    }
                    jdone = r;
                }
                const int dist = i - jdone;
                if (dist <= 4) break;
                if (!prog) {
                    if (dist > 24)      __builtin_amdgcn_s_sleep(32);
                    else if (dist > 10) __builtin_amdgcn_s_sleep(8);
                    else                __builtin_amdgcn_s_sleep(1);
                }
            }
            // --- tail (<=4 regions): two-stream sentinel poll; A-coeffs preloaded ---
            const int n = i - jdone;
            if (n > 0) {
                const int jc1 = min(jdone + 1, i - 1);
                const int jc2 = min(jdone + 2, i - 1);
                const int jc3 = min(jdone + 3, i - 1);
                const float aj0 = A[(size_t)jdone * NR + i];
                const float aj1 = A[(size_t)jc1 * NR + i];
                const float aj2 = A[(size_t)jc2 * NR + i];
                const float aj3 = A[(size_t)jc3 * NR + i];
#define TCONS(K, JK, AJ)                                                        \
                if (K < n) {                                                    \
                    const float* p0 = delta + (size_t)(JK) * TT + 4 * tid;      \
                    float o0,o1,o2,o3,o4,o5,o6,o7;                              \
                    poll8_2s(p0, p0 + 1024, o0,o1,o2,o3,o4,o5,o6,o7);           \
                    r0.x = fmaf(AJ, o0, r0.x); r0.y = fmaf(AJ, o1, r0.y);       \
                    r0.z = fmaf(AJ, o2, r0.z); r0.w = fmaf(AJ, o3, r0.w);       \
                    r1.x = fmaf(AJ, o4, r1.x); r1.y = fmaf(AJ, o5, r1.y);       \
                    r1.z = fmaf(AJ, o6, r1.z); r1.w = fmaf(AJ, o7, r1.w);       \
                }
                TCONS(0, jdone, aj0)
                TCONS(1, jc1, aj1)
                TCONS(2, jc2, aj2)
                TCONS(3, jc3, aj3)
#undef TCONS
            }
        }

        // --- publish x into LDS (float4-aligned in padded layout), one barrier ---
        {
            const int e0 = 4 * tid;
            const int e1 = 4 * tid + 1024;
            *(float4*)&xs[xidx(e0 >> 9, e0 & 511)] = r0;
            *(float4*)&xs[xidx(e1 >> 9, e1 & 511)] = r1;
        }
        __syncthreads();

        // --- GEMM: pred[b][kg] = sum_m x[b][m]*W[m][kg]; chains identical to R9 ---
        float acc0 = 0.f, acc1 = 0.f, acc2 = 0.f, acc3 = 0.f;
#pragma unroll
        for (int s4 = 0; s4 < 32; s4++) {
            const int mb = mq * QSTR + s4 * 4;
            float4 x0 = *(const float4*)&xs[mb];
            float4 x1 = *(const float4*)&xs[BSTR + mb];
            float4 x2 = *(const float4*)&xs[2 * BSTR + mb];
            float4 x3 = *(const float4*)&xs[3 * BSTR + mb];
            const float w0 = w[s4 * 4], w1 = w[s4 * 4 + 1], w2 = w[s4 * 4 + 2], w3 = w[s4 * 4 + 3];
            acc0 += x0.x * w0 + x0.y * w1 + x0.z * w2 + x0.w * w3;
            acc1 += x1.x * w0 + x1.y * w1 + x1.z * w2 + x1.w * w3;
            acc2 += x2.x * w0 + x2.y * w1 + x2.z * w2 + x2.w * w3;
            acc3 += x3.x * w0 + x3.y * w1 + x3.z * w2 + x3.w * w3;
        }
        acc0 += __shfl_xor(acc0, 1); acc0 += __shfl_xor(acc0, 2);
        acc1 += __shfl_xor(acc1, 1); acc1 += __shfl_xor(acc1, 2);
        acc2 += __shfl_xor(acc2, 1); acc2 += __shfl_xor(acc2, 2);
        acc3 += __shfl_xor(acc3, 1); acc3 += __shfl_xor(acc3, 2);
        const float pred = (mq == 0) ? acc0 : (mq == 1) ? acc1 : (mq == 2) ? acc2 : acc3;

        // --- state update; delta sc1 store FIRST (the signal) ---
        const float vb  = TAU * vb0v + OMT * pred;
        const float va  = TAU * va0v;
        const float vs  = TAU * vsi + OMT * (vb - va);
        __hip_atomic_store(&delta[base], vs - vsi, __ATOMIC_RELAXED, __HIP_MEMORY_SCOPE_AGENT);
        const float mis = vs - vb;

        // --- lazy flag publish (bulk-path hint; off reader critical path) ---
        asm volatile("s_waitcnt vmcnt(0)" ::: "memory");   // delta in IC before flag
        {
            const int slot = (qq << 2) + wv;
            for (int r = i + 1 + lane; r < NR; r += 64)
                __hip_atomic_store(&flagmat[r * 32 + slot], i + 1,
                                   __ATOMIC_RELAXED, __HIP_MEMORY_SCOPE_AGENT);
        }
        out_sp[base] = (vs > 0.f) ? 1.f : 0.f;
        __syncthreads();   // protect xs: GEMM reads done before rbar overwrite

        // --- fused Hebbian (off critical path): rbar in-place into xs, float4 ---
#pragma unroll
        for (int s = 0; s < 2; s++) {
            const int e = 4 * tid + s * 1024;
            float* xp = &xs[xidx(e >> 9, e & 511)];
            const float4 rr = ((const float4*)(rbar0 + (size_t)i * TT))[tid + s * 256];
            float4 xv = *(float4*)xp;
            xv.x = OMA * rr.x + ALPH * xv.x; xv.y = OMA * rr.y + ALPH * xv.y;
            xv.z = OMA * rr.z + ALPH * xv.z; xv.w = OMA * rr.w + ALPH * xv.w;
            *(float4*)xp = xv;
        }
        __syncthreads();

        const float e_own = OMA * eb0v + ALPH * mis;
        const int qb = lane & ~3;
        const float e0 = __shfl(e_own, qb + 0);
        const float e1 = __shfl(e_own, qb + 1);
        const float e2 = __shfl(e_own, qb + 2);
        const float e3 = __shfl(e_own, qb + 3);

        // vectorized LDS reads (same per-element expression tree -> bit-exact),
        // nontemporal outW stores (don't thrash L2 used by gather)
#pragma unroll
        for (int s4 = 0; s4 < 32; s4++) {
            const int xo = mq * QSTR + s4 * 4;
            const float4 X0 = *(const float4*)&xs[xo];
            const float4 X1 = *(const float4*)&xs[BSTR + xo];
            const float4 X2 = *(const float4*)&xs[2 * BSTR + xo];
            const float4 X3 = *(const float4*)&xs[3 * BSTR + xo];
            const int m0 = mq * 128 + s4 * 4;
            float* op = &outW[(((size_t)i * NN + m0) * NN) + kg];
            __builtin_nontemporal_store(w[s4*4+0] + LRQ * (e0*X0.x + e1*X1.x + e2*X2.x + e3*X3.x), op);
            __builtin_nontemporal_store(w[s4*4+1] + LRQ * (e0*X0.y + e1*X1.y + e2*X2.y + e3*X3.y), op + NN);
            __builtin_nontemporal_store(w[s4*4+2] + LRQ * (e0*X0.z + e1*X1.z + e2*X2.z + e3*X3.z), op + 2*NN);
            __builtin_nontemporal_store(w[s4*4+3] + LRQ * (e0*X0.w + e1*X1.w + e2*X2.w + e3*X3.w), op + 3*NN);
        }

        // --- F partial (deterministic per-block double) ---
        double p = (double)mis * (double)mis;
#pragma unroll
        for (int off = 32; off; off >>= 1) p += __shfl_xor(p, off);
        if (lane == 0) ps[wv] = p;
        __syncthreads();
        if (tid == 0) fpart[(size_t)i * SLC + qq] = ps[0] + ps[1] + ps[2] + ps[3];
        __syncthreads();   // ps consumed before next iteration rewrites it
    }
}

// ---------------- final F reduction ----------------
__global__ __launch_bounds__(256) void k_fin(const double* __restrict__ fpart,
                                             float* __restrict__ outF) {
    __shared__ double ps[256];
    double s = 0.0;
    for (int idx = threadIdx.x; idx < NR * SLC; idx += 256) s += fpart[idx];
    ps[threadIdx.x] = s;
    __syncthreads();
    for (int st = 128; st; st >>= 1) {
        if (threadIdx.x < st) ps[threadIdx.x] += ps[threadIdx.x + st];
        __syncthreads();
    }
    if (threadIdx.x == 0) outF[0] = (float)(ps[0] / 614400.0);
}

extern "C" void kernel_launch(void* const* d_in, const int* in_sizes, int n_in,
                              void* d_out, int out_size, void* d_ws, size_t ws_size,
                              hipStream_t stream) {
    const float* v_s0  = (const float*)d_in[0];
    const float* v_b0  = (const float*)d_in[1];
    const float* v_a0  = (const float*)d_in[2];
    const float* rbar0 = (const float*)d_in[3];
    const float* ebar0 = (const float*)d_in[4];
    const float* W     = (const float*)d_in[5];
    const float* A     = (const float*)d_in[6];
    const float* inp   = (const float*)d_in[7];
    const float* noise = (const float*)d_in[8];

    float* out_sp = (float*)d_out;                 // [300,4,512]
    float* out_W  = out_sp + 614400;               // [300,512,512]
    float* out_F  = out_sp + 79257600;             // scalar

    char* ws = (char*)d_ws;
    float* v_init  = (float*)ws;                       // 614400 f
    float* X       = v_init + 614400;                  // 614400 f
    float* delta   = X + 614400;                       // 614400 f @ byte 4915200
    int*   flagmat = (int*)(ws + 7372800);             // 300 rows x 32 ints (128B rows)
    double* fpart  = (double*)(ws + 7411200);          // 2400 doubles

    // one memset covers delta sentinel (0xFFFFFFFF = NaN) AND flagmat (-1)
    (void)hipMemsetAsync(delta, 0xFF, 2457600 + NR * 32 * sizeof(int), stream);
    k_init<<<600, 256, 0, stream>>>(v_s0, noise, v_init);
    k_base<<<120, 256, 0, stream>>>(A, v_init, inp, X);
    k_chain<<<CH * SLC, 256, 0, stream>>>(W, v_b0, v_a0, A, v_init, X,
                                          rbar0, ebar0, delta, flagmat,
                                          out_sp, out_W, fpart);
    k_fin<<<1, 256, 0, stream>>>(fpart, out_F);
}